// Round 15
// baseline (2013.545 us; speedup 1.0000x reference)
//
#include <hip/hip_runtime.h>
#include <stdint.h>

typedef __attribute__((ext_vector_type(8))) short short8;
typedef __attribute__((ext_vector_type(4))) float f32x4;
typedef __attribute__((address_space(3))) void lds_void;
typedef __attribute__((address_space(1))) void gv_void;

static __device__ __forceinline__ float bf2f(unsigned short u) {
    union { uint32_t i; float f; } v; v.i = ((uint32_t)u) << 16; return v.f;
}
static __device__ __forceinline__ unsigned short f2bf(float f) {
    union { float f; uint32_t i; } v; v.f = f;
    uint32_t i = v.i;
    uint32_t r = (i + 0x7fffu + ((i >> 16) & 1u)) >> 16;
    return (unsigned short)r;
}
static __device__ __forceinline__ float fexp(float x) {
    float r;
    asm("v_exp_f32 %0, %1" : "=v"(r) : "v"(x * 1.44269504088896f));
    return r;
}
static __device__ __forceinline__ float frcp(float x) {
    float r;
    asm("v_rcp_f32 %0, %1" : "=v"(r) : "v"(x));
    return r;
}

// ---------------------------------------------------------------------------
__global__ void k_detect(const void* __restrict__ g1, int* __restrict__ flag) {
    if (threadIdx.x == 0 && blockIdx.x == 0) {
        const unsigned short* u = (const unsigned short*)g1;
        flag[0] = (u[0] == 0x3F80u) ? 0 : 1;
    }
}

__global__ __launch_bounds__(256) void k_cvt(const void* __restrict__ src,
                                             unsigned short* __restrict__ dst,
                                             int n, const int* __restrict__ flag) {
    int i = blockIdx.x * 256 + threadIdx.x;
    if (i < n) {
        dst[i] = flag[0] ? f2bf(((const float*)src)[i])
                         : ((const unsigned short*)src)[i];
    }
}

// ---------------------------------------------------------------------------
__global__ __launch_bounds__(256) void k_transpose(const void* __restrict__ in,
                                                   unsigned short* __restrict__ out,
                                                   int R, int C, const int* __restrict__ flag) {
    __shared__ unsigned short tile[32][33];
    int isf = flag[0];
    int tx = threadIdx.x, ty = threadIdx.y;
    int x = blockIdx.x * 32 + tx;
    int y0 = blockIdx.y * 32;
    for (int j = ty; j < 32; j += 8) {
        size_t idx = (size_t)(y0 + j) * C + x;
        tile[j][tx] = isf ? f2bf(((const float*)in)[idx]) : ((const unsigned short*)in)[idx];
    }
    __syncthreads();
    int x2 = y0 + tx;
    int y20 = blockIdx.x * 32;
    for (int j = ty; j < 32; j += 8)
        out[(size_t)(y20 + j) * R + x2] = tile[tx][j];
}

// ---------------------------------------------------------------------------
// bias[h][q][k] f32 = bias_table[rel_idx[q,k]][h]
// ---------------------------------------------------------------------------
__global__ __launch_bounds__(256) void k_prep_bias(const void* __restrict__ bias_table,
                                                   const int* __restrict__ rel_idx,
                                                   float* __restrict__ biasp,
                                                   const int* __restrict__ flag) {
    int i = blockIdx.x * 256 + threadIdx.x;   // 65536 total
    int isf = flag[0];
    int h = i & 15, qk = i >> 4;
    size_t idx = (size_t)rel_idx[qk] * 16 + h;
    float v = isf ? ((const float*)bias_table)[idx] : bf2f(((const unsigned short*)bias_table)[idx]);
    biasp[h * 4096 + qk] = v;
}

// ---------------------------------------------------------------------------
__global__ __launch_bounds__(256) void k_partition_ln(const void* __restrict__ x,
                                                      const unsigned short* __restrict__ g1,
                                                      const unsigned short* __restrict__ b1,
                                                      unsigned short* __restrict__ xw,
                                                      unsigned short* __restrict__ h,
                                                      int b0, const int* __restrict__ flag) {
    __shared__ unsigned short tile[64][512];
    int isf = flag[0];
    int bh = blockIdx.x, bl = bh >> 6, hh = bh & 63;
    int b = b0 + bl;
    int tid = threadIdx.x;
    size_t xoff = (((size_t)b * 512) * 64 + hh) * 64;
    int c0 = tid >> 3, ch = tid & 7;
    if (isf) {
        const float* xb = (const float*)x + xoff;
        for (int k = 0; k < 16; ++k) {
            int c = c0 + k * 32;
            f32x4 v0 = *reinterpret_cast<const f32x4*>(xb + (size_t)c * 4096 + ch * 8);
            f32x4 v1 = *reinterpret_cast<const f32x4*>(xb + (size_t)c * 4096 + ch * 8 + 4);
#pragma unroll
            for (int j = 0; j < 4; ++j) tile[ch * 8 + j][c] = f2bf(v0[j]);
#pragma unroll
            for (int j = 0; j < 4; ++j) tile[ch * 8 + 4 + j][c] = f2bf(v1[j]);
        }
    } else {
        const unsigned short* xb = (const unsigned short*)x + xoff;
        for (int k = 0; k < 16; ++k) {
            int c = c0 + k * 32;
            short8 v = *reinterpret_cast<const short8*>(xb + (size_t)c * 4096 + ch * 8);
#pragma unroll
            for (int j = 0; j < 8; ++j) tile[ch * 8 + j][c] = (unsigned short)v[j];
        }
    }
    __syncthreads();
    int w = tid >> 2, q = tid & 3;
    float s = 0.f, s2 = 0.f;
#pragma unroll 4
    for (int j = 0; j < 128; ++j) {
        int c = q * 128 + ((j + 8 * w) & 127);
        float f = bf2f(tile[w][c]);
        s += f; s2 += f * f;
    }
    s += __shfl_xor(s, 1);  s += __shfl_xor(s, 2);
    s2 += __shfl_xor(s2, 1); s2 += __shfl_xor(s2, 2);
    float mu = s * (1.f / 512.f);
    float rstd = rsqrtf(s2 * (1.f / 512.f) - mu * mu + 1e-5f);
    int t = (bl * 64 + (hh >> 3) * 8 + (w >> 3)) * 64 + (hh & 7) * 8 + (w & 7);
    unsigned short* xr = xw + (size_t)t * 512;
    unsigned short* hr = h + (size_t)t * 512;
    for (int cc = q * 128; cc < q * 128 + 128; cc += 8) {
        short8 raw, hn;
#pragma unroll
        for (int j = 0; j < 8; ++j) {
            unsigned short u = tile[w][cc + j];
            raw[j] = (short)u;
            float f = (bf2f(u) - mu) * rstd * bf2f(g1[cc + j]) + bf2f(b1[cc + j]);
            hn[j] = (short)f2bf(f);
        }
        *reinterpret_cast<short8*>(xr + cc) = raw;
        *reinterpret_cast<short8*>(hr + cc) = hn;
    }
}

// ---------------------------------------------------------------------------
__global__ __launch_bounds__(256) void k_ln(const unsigned short* __restrict__ in,
                                            const unsigned short* __restrict__ g,
                                            const unsigned short* __restrict__ b,
                                            unsigned short* __restrict__ out) {
    int wid = threadIdx.x >> 6, lane = threadIdx.x & 63;
    size_t t = (size_t)blockIdx.x * 4 + wid;
    short8 v = *reinterpret_cast<const short8*>(in + t * 512 + lane * 8);
    float f[8], s = 0.f, s2 = 0.f;
#pragma unroll
    for (int j = 0; j < 8; ++j) { f[j] = bf2f((unsigned short)v[j]); s += f[j]; s2 += f[j] * f[j]; }
    for (int m = 1; m < 64; m <<= 1) { s += __shfl_xor(s, m); s2 += __shfl_xor(s2, m); }
    float mu = s * (1.f / 512.f);
    float rstd = rsqrtf(s2 * (1.f / 512.f) - mu * mu + 1e-5f);
    short8 ov;
#pragma unroll
    for (int j = 0; j < 8; ++j)
        ov[j] = (short)f2bf((f[j] - mu) * rstd * bf2f(g[lane * 8 + j]) + bf2f(b[lane * 8 + j]));
    *reinterpret_cast<short8*>(out + t * 512 + lane * 8) = ov;
}

// ---------------------------------------------------------------------------
// GEMM 256x256 (R6 loop + R12 grouping), half-K(32) 4-slot LDS ring,
// counted vmcnt(12/8/4/0), XOR swizzle, setprio, XCD chunking, GROUP_M=8.
// Two-pass epilogue (3 barriers; 2-way-conflict LDS writes; each thread
// stores a full 64-element / 128 B contiguous run — R14's bug was storing
// only 32 of the 64 elements).  MODE 0: +bias. 1: +bias+res. 2: +bias+GELU.
// Requires nwg % 8 == 0 and gridDim.x % 8 == 0.
// ---------------------------------------------------------------------------
template <int MODE>
__global__ __launch_bounds__(512, 1) void k_gemm16(const unsigned short* __restrict__ A,
                                                   const unsigned short* __restrict__ BT,
                                                   const unsigned short* __restrict__ bias,
                                                   const unsigned short* __restrict__ res,
                                                   unsigned short* __restrict__ out,
                                                   int M, int N, int K) {
    __shared__ unsigned short S[65536];        // 4 slots x (A 8192 + B 8192 elems)
    const int tid = threadIdx.x, lane = tid & 63, wid = tid >> 6;

    int nwg = gridDim.x * gridDim.y;
    int lin = blockIdx.y * gridDim.x + blockIdx.x;
    int swz = (lin & 7) * (nwg >> 3) + (lin >> 3);
    const int G = 8;
    int width = G * gridDim.y;
    int group = swz / width;
    int rem   = swz % width;
    int mt = group * G + (rem % G);
    int nt = rem / G;

    const int wr = wid >> 2, wc = wid & 3;
    const int rl = lane & 15, qg = lane >> 4;

    const int strow = tid >> 2;
    const int scb   = (tid & 3) ^ ((tid >> 3) & 3);
    const unsigned short* Agb = A  + ((size_t)mt * 256 + strow) * K + scb * 8;
    const unsigned short* Bgb = BT + ((size_t)nt * 256 + strow) * K + scb * 8;
    const int ldst = strow * 32 + (tid & 3) * 8;

    f32x4 acc[8][4];
#pragma unroll
    for (int mf = 0; mf < 8; ++mf)
#pragma unroll
        for (int nf = 0; nf < 4; ++nf) {
            acc[mf][nf][0] = 0.f; acc[mf][nf][1] = 0.f; acc[mf][nf][2] = 0.f; acc[mf][nf][3] = 0.f;
        }

    const int NH = K >> 5;

    auto stage = [&](int h) {                  // 4 vmcnt units per call
        int base = (h & 3) * 16384;
#pragma unroll
        for (int s = 0; s < 2; ++s) {
            __builtin_amdgcn_global_load_lds((const gv_void*)(Agb + (size_t)s * 128 * K + h * 32),
                                             (lds_void*)(&S[base + s * 4096 + ldst]), 16, 0, 0);
            __builtin_amdgcn_global_load_lds((const gv_void*)(Bgb + (size_t)s * 128 * K + h * 32),
                                             (lds_void*)(&S[base + 8192 + s * 4096 + ldst]), 16, 0, 0);
        }
    };

    stage(0); stage(1); stage(2);              // 12 loads in flight

    const int arow0 = wr * 128 + rl;
    const int brow0 = wc * 64 + rl;
    const int kbr = (qg ^ ((rl >> 1) & 3)) * 8;

    for (int h = 0; h < NH; ++h) {
        const unsigned short* sA = &S[(h & 3) * 16384];
        const unsigned short* sB = sA + 8192;
        if (h + 3 < NH) {
            stage(h + 3);
            asm volatile("s_waitcnt vmcnt(12)" ::: "memory");
        } else if (h + 2 < NH) {
            asm volatile("s_waitcnt vmcnt(8)" ::: "memory");
        } else if (h + 1 < NH) {
            asm volatile("s_waitcnt vmcnt(4)" ::: "memory");
        } else {
            asm volatile("s_waitcnt vmcnt(0)" ::: "memory");
        }
        __builtin_amdgcn_s_barrier();
        asm volatile("" ::: "memory");

        short8 af[8], bfr[4];
#pragma unroll
        for (int nf = 0; nf < 4; ++nf)
            bfr[nf] = *reinterpret_cast<const short8*>(&sB[(brow0 + nf * 16) * 32 + kbr]);
#pragma unroll
        for (int mf = 0; mf < 8; ++mf)
            af[mf] = *reinterpret_cast<const short8*>(&sA[(arow0 + mf * 16) * 32 + kbr]);

        __builtin_amdgcn_s_setprio(1);
#pragma unroll
        for (int mf = 0; mf < 8; ++mf)
#pragma unroll
            for (int nf = 0; nf < 4; ++nf)
                acc[mf][nf] = __builtin_amdgcn_mfma_f32_16x16x32_bf16(af[mf], bfr[nf], acc[mf][nf], 0, 0, 0);
        __builtin_amdgcn_s_setprio(0);

        __builtin_amdgcn_s_barrier();
        asm volatile("" ::: "memory");
    }

    // ---- epilogue: two-pass LDS bounce (128 rows x 264 each), 3 barriers
    const int PST = 264;
    unsigned short* pb = (unsigned short*)S;
    float bz[4];
#pragma unroll
    for (int nf = 0; nf < 4; ++nf) bz[nf] = bf2f(bias[nt * 256 + wc * 64 + nf * 16 + rl]);
    const int row_l = tid >> 2;                // 0..127
    const int cseg  = (tid & 3) * 64;          // 0..192 (64-element / 128 B runs)
    const int wrg = row_l >> 6, jrem = (row_l >> 4) & 3, sub = row_l & 15;

#pragma unroll
    for (int mp = 0; mp < 2; ++mp) {
        if (mp) __syncthreads();               // protect pass-0 reads before overwrite
#pragma unroll
        for (int j = 0; j < 4; ++j) {
            int mf = mp * 4 + j;
#pragma unroll
            for (int nf = 0; nf < 4; ++nf)
#pragma unroll
                for (int r = 0; r < 4; ++r) {
                    float v = acc[mf][nf][r] + bz[nf];
                    if (MODE == 2) {
                        float z = 0.7978845608f * (v + 0.044715f * v * v * v);
                        float e = fexp(-2.0f * z);           // gelu = v * sigmoid(2z)
                        v = v * frcp(1.f + e);
                    }
                    pb[(wr * 64 + j * 16 + qg * 4 + r) * PST + wc * 64 + nf * 16 + rl] = f2bf(v);
                }
        }
        __syncthreads();
        int grow = mt * 256 + wrg * 128 + (mp * 4 + jrem) * 16 + sub;
        size_t go = (size_t)grow * N + nt * 256 + cseg;
        const unsigned short* prow = &pb[row_l * PST + cseg];
        short8 ov[8];
#pragma unroll
        for (int s = 0; s < 8; ++s) ov[s] = *reinterpret_cast<const short8*>(prow + s * 8);
        if (MODE == 1) {
#pragma unroll
            for (int s = 0; s < 8; ++s) {
                short8 rv = *reinterpret_cast<const short8*>(&res[go + s * 8]);
#pragma unroll
                for (int jj = 0; jj < 8; ++jj)
                    ov[s][jj] = (short)f2bf(bf2f((unsigned short)ov[s][jj]) + bf2f((unsigned short)rv[jj]));
            }
        }
#pragma unroll
        for (int s = 0; s < 8; ++s)
            *reinterpret_cast<short8*>(&out[go + s * 8]) = ov[s];
    }
}

// ---------------------------------------------------------------------------
// Windowed attention (R6): one wave per (window, head), fast exp/rcp.
// ---------------------------------------------------------------------------
__global__ __launch_bounds__(64) void k_attn(const unsigned short* __restrict__ qkv,
                                             const float* __restrict__ biasp,
                                             unsigned short* __restrict__ o) {
    __shared__ unsigned short Pl[64][72];
    int blk = blockIdx.x;
    int head = blk & 15, win = blk >> 4;
    size_t T0 = (size_t)win * 64;
    int lane = threadIdx.x;
    int rl = lane & 15, qg = lane >> 4;
    const unsigned short* base = qkv + T0 * 1536;
    int qoff = head * 32, koff = 512 + head * 32, voff = 1024 + head * 32;

    f32x4 s[4][4];
#pragma unroll
    for (int m = 0; m < 4; ++m)
#pragma unroll
        for (int n = 0; n < 4; ++n) { s[m][n][0] = 0.f; s[m][n][1] = 0.f; s[m][n][2] = 0.f; s[m][n][3] = 0.f; }

    short8 aq[4], bk[4];
#pragma unroll
    for (int m = 0; m < 4; ++m)
        aq[m] = *reinterpret_cast<const short8*>(base + (size_t)(16 * m + rl) * 1536 + qoff + qg * 8);
#pragma unroll
    for (int n = 0; n < 4; ++n)
        bk[n] = *reinterpret_cast<const short8*>(base + (size_t)(16 * n + rl) * 1536 + koff + qg * 8);
#pragma unroll
    for (int m = 0; m < 4; ++m)
#pragma unroll
        for (int n = 0; n < 4; ++n)
            s[m][n] = __builtin_amdgcn_mfma_f32_16x16x32_bf16(aq[m], bk[n], s[m][n], 0, 0, 0);

    const float scale = 0.17677669529663687f;
    const float* bh = biasp + head * 4096;
#pragma unroll
    for (int m = 0; m < 4; ++m) {
#pragma unroll
        for (int r = 0; r < 4; ++r) {
            int row = 16 * m + qg * 4 + r;
            float v0 = s[m][0][r] * scale + bh[row * 64 + rl];
            float v1 = s[m][1][r] * scale + bh[row * 64 + 16 + rl];
            float v2 = s[m][2][r] * scale + bh[row * 64 + 32 + rl];
            float v3 = s[m][3][r] * scale + bh[row * 64 + 48 + rl];
            float mx = fmaxf(fmaxf(v0, v1), fmaxf(v2, v3));
            mx = fmaxf(mx, __shfl_xor(mx, 1));
            mx = fmaxf(mx, __shfl_xor(mx, 2));
            mx = fmaxf(mx, __shfl_xor(mx, 4));
            mx = fmaxf(mx, __shfl_xor(mx, 8));
            v0 = fexp(v0 - mx); v1 = fexp(v1 - mx); v2 = fexp(v2 - mx); v3 = fexp(v3 - mx);
            float sm = v0 + v1 + v2 + v3;
            sm += __shfl_xor(sm, 1);
            sm += __shfl_xor(sm, 2);
            sm += __shfl_xor(sm, 4);
            sm += __shfl_xor(sm, 8);
            float inv = frcp(sm);
            Pl[row][rl]      = f2bf(v0 * inv);
            Pl[row][16 + rl] = f2bf(v1 * inv);
            Pl[row][32 + rl] = f2bf(v2 * inv);
            Pl[row][48 + rl] = f2bf(v3 * inv);
        }
    }
    __syncthreads();

    short8 bv[2][2];
#pragma unroll
    for (int ks = 0; ks < 2; ++ks)
#pragma unroll
        for (int n2 = 0; n2 < 2; ++n2) {
            short8 t;
#pragma unroll
            for (int i = 0; i < 8; ++i)
                t[i] = (short)base[(size_t)(32 * ks + qg * 8 + i) * 1536 + voff + n2 * 16 + rl];
            bv[ks][n2] = t;
        }

    f32x4 acc2[4][2];
#pragma unroll
    for (int m = 0; m < 4; ++m)
#pragma unroll
        for (int n2 = 0; n2 < 2; ++n2) { acc2[m][n2][0] = 0.f; acc2[m][n2][1] = 0.f; acc2[m][n2][2] = 0.f; acc2[m][n2][3] = 0.f; }

#pragma unroll
    for (int m = 0; m < 4; ++m) {
        short8 p0 = *reinterpret_cast<const short8*>(&Pl[16 * m + rl][qg * 8]);
        short8 p1 = *reinterpret_cast<const short8*>(&Pl[16 * m + rl][32 + qg * 8]);
#pragma unroll
        for (int n2 = 0; n2 < 2; ++n2) {
            acc2[m][n2] = __builtin_amdgcn_mfma_f32_16x16x32_bf16(p0, bv[0][n2], acc2[m][n2], 0, 0, 0);
            acc2[m][n2] = __builtin_amdgcn_mfma_f32_16x16x32_bf16(p1, bv[1][n2], acc2[m][n2], 0, 0, 0);
        }
    }
#pragma unroll
    for (int m = 0; m < 4; ++m)
#pragma unroll
        for (int n2 = 0; n2 < 2; ++n2)
#pragma unroll
            for (int r = 0; r < 4; ++r) {
                int row = 16 * m + qg * 4 + r;
                o[(T0 + row) * 512 + head * 32 + n2 * 16 + rl] = f2bf(acc2[m][n2][r]);
            }
}

// ---------------------------------------------------------------------------
// Window-departition: tokens[t_local][c] -> x[B,C,H,W] (coalesced via LDS)
// ---------------------------------------------------------------------------
__global__ __launch_bounds__(256) void k_departition(const unsigned short* __restrict__ tok,
                                                     void* __restrict__ xo,
                                                     int b0, const int* __restrict__ flag) {
    __shared__ unsigned short tile[64][512];
    int isf = flag[0];
    int bh = blockIdx.x, bl = bh >> 6, hh = bh & 63;
    int b = b0 + bl;
    int tid = threadIdx.x;
    int Tb = (bl * 64 + (hh >> 3) * 8) * 64 + (hh & 7) * 8;
    for (int k = 0; k < 16; ++k) {
        int flat = k * 256 + tid;
        int w = flat >> 6, ch = flat & 63;
        int t = Tb + (w >> 3) * 64 + (w & 7);
        short8 v = *reinterpret_cast<const short8*>(tok + (size_t)t * 512 + ch * 8);
        *reinterpret_cast<short8*>(&tile[w][ch * 8]) = v;
    }
    __syncthreads();
    size_t xoff = (((size_t)b * 512) * 64 + hh) * 64;
    if (isf) {
        float* xb = (float*)xo + xoff;
        for (int k = 0; k < 16; ++k) {
            int flat = k * 256 + tid;
            int c = flat >> 3, wc = flat & 7;
            f32x4 a, d;
#pragma unroll
            for (int j = 0; j < 4; ++j) a[j] = bf2f(tile[wc * 8 + j][c]);
#pragma unroll
            for (int j = 0; j < 4; ++j) d[j] = bf2f(tile[wc * 8 + 4 + j][c]);
            *reinterpret_cast<f32x4*>(xb + (size_t)c * 4096 + wc * 8) = a;
            *reinterpret_cast<f32x4*>(xb + (size_t)c * 4096 + wc * 8 + 4) = d;
        }
    } else {
        unsigned short* xb = (unsigned short*)xo + xoff;
        for (int k = 0; k < 16; ++k) {
            int flat = k * 256 + tid;
            int c = flat >> 3, wc = flat & 7;
            short8 v;
#pragma unroll
            for (int j = 0; j < 8; ++j) v[j] = (short)tile[wc * 8 + j][c];
            *reinterpret_cast<short8*>(xb + (size_t)c * 4096 + wc * 8) = v;
        }
    }
}

// ---------------------------------------------------------------------------
extern "C" void kernel_launch(void* const* d_in, const int* in_sizes, int n_in,
                              void* d_out, int out_size, void* d_ws, size_t ws_size,
                              hipStream_t stream) {
    const void* x          = d_in[0];
    const void* g1         = d_in[1];
    const void* be1        = d_in[2];
    const void* g2         = d_in[3];
    const void* be2        = d_in[4];
    const void* qkv_w      = d_in[5];
    const void* qkv_b      = d_in[6];
    const void* merge_w    = d_in[7];
    const void* merge_b    = d_in[8];
    const void* bias_table = d_in[9];
    const void* w1         = d_in[10];
    const void* b1         = d_in[11];
    const void* w2         = d_in[12];
    const void* b2         = d_in[13];
    const int*  rel_idx    = (const int*)d_in[14];

    // Per-token ws need = 9216 B (xw 1024 + h 1024 + qkv 3072 + mid 4096).
    const size_t extra = 8u << 20;
    int CB = 4;
    if      (ws_size >= (size_t)131072 * 9216 + extra) CB = 32;
    else if (ws_size >= (size_t)65536  * 9216 + extra) CB = 16;
    else if (ws_size >= (size_t)32768  * 9216 + extra) CB = 8;
    int nch = 32 / CB;
    size_t tok = (size_t)CB * 4096;

    unsigned short* xw_c     = (unsigned short*)d_ws;
    unsigned short* h_c      = xw_c + tok * 512;
    unsigned short* qkv_c    = h_c + tok * 512;
    unsigned short* mid_c    = qkv_c + tok * 1536;
    unsigned short* qkv_wT   = mid_c + tok * 2048;
    unsigned short* merge_wT = qkv_wT + 1536 * 512;
    unsigned short* w1T      = merge_wT + 512 * 512;
    unsigned short* w2T      = w1T + 2048 * 512;
    unsigned short* vecs     = w2T + 512 * 2048;
    float*          biasp    = (float*)(vecs + 6656);
    int*            flag     = (int*)(biasp + 65536);

    unsigned short* ng1 = vecs + 0,    *nbe1 = vecs + 512;
    unsigned short* ng2 = vecs + 1024, *nbe2 = vecs + 1536;
    unsigned short* nqb = vecs + 2048, *nmb  = vecs + 3584;
    unsigned short* nb1 = vecs + 4096, *nb2  = vecs + 6144;

    // --- prep
    k_detect<<<1, 64, 0, stream>>>(g1, flag);
    k_cvt<<<2, 256, 0, stream>>>(g1, ng1, 512, flag);
    k_cvt<<<2, 256, 0, stream>>>(be1, nbe1, 512, flag);
    k_cvt<<<2, 256, 0, stream>>>(g2, ng2, 512, flag);
    k_cvt<<<2, 256, 0, stream>>>(be2, nbe2, 512, flag);
    k_cvt<<<6, 256, 0, stream>>>(qkv_b, nqb, 1536, flag);
    k_cvt<<<2, 256, 0, stream>>>(merge_b, nmb, 512, flag);
    k_cvt<<<8, 256, 0, stream>>>(b1, nb1, 2048, flag);
    k_cvt<<<2, 256, 0, stream>>>(b2, nb2, 512, flag);
    k_transpose<<<dim3(48, 16), dim3(32, 8), 0, stream>>>(qkv_w, qkv_wT, 512, 1536, flag);
    k_transpose<<<dim3(16, 16), dim3(32, 8), 0, stream>>>(merge_w, merge_wT, 512, 512, flag);
    k_transpose<<<dim3(64, 16), dim3(32, 8), 0, stream>>>(w1, w1T, 512, 2048, flag);
    k_transpose<<<dim3(16, 64), dim3(32, 8), 0, stream>>>(w2, w2T, 2048, 512, flag);
    k_prep_bias<<<256, 256, 0, stream>>>(bias_table, rel_idx, biasp, flag);

    int mtiles = (int)(tok / 256);
    int M = (int)tok;
    for (int c = 0; c < nch; ++c) {
        int b0 = c * CB;
        k_partition_ln<<<CB * 64, 256, 0, stream>>>(x, ng1, nbe1, xw_c, h_c, b0, flag);
        k_gemm16<0><<<dim3(mtiles, 6), 512, 0, stream>>>(h_c, qkv_wT, nqb, nullptr, qkv_c, M, 1536, 512);
        k_attn<<<CB * 1024, 64, 0, stream>>>(qkv_c, biasp, h_c);            // o -> h_c (h dead)
        k_gemm16<1><<<dim3(mtiles, 2), 512, 0, stream>>>(h_c, merge_wT, nmb, xw_c, xw_c, M, 512, 512);
        k_ln<<<(int)(tok / 4), 256, 0, stream>>>(xw_c, ng2, nbe2, h_c);
        k_gemm16<2><<<dim3(mtiles, 8), 512, 0, stream>>>(h_c, w1T, nb1, nullptr, mid_c, M, 2048, 512);
        k_gemm16<1><<<dim3(mtiles, 2), 512, 0, stream>>>(mid_c, w2T, nb2, xw_c, qkv_c, M, 512, 2048);
        k_departition<<<CB * 64, 256, 0, stream>>>(qkv_c, d_out, b0, flag);
    }
}

// Round 16
// 1793.115 us; speedup vs baseline: 1.1229x; 1.1229x over previous
//
#include <hip/hip_runtime.h>
#include <stdint.h>

typedef __attribute__((ext_vector_type(8))) short short8;
typedef __attribute__((ext_vector_type(4))) float f32x4;
typedef __attribute__((address_space(3))) void lds_void;
typedef __attribute__((address_space(1))) void gv_void;

static __device__ __forceinline__ float bf2f(unsigned short u) {
    union { uint32_t i; float f; } v; v.i = ((uint32_t)u) << 16; return v.f;
}
static __device__ __forceinline__ unsigned short f2bf(float f) {
    union { float f; uint32_t i; } v; v.f = f;
    uint32_t i = v.i;
    uint32_t r = (i + 0x7fffu + ((i >> 16) & 1u)) >> 16;
    return (unsigned short)r;
}
static __device__ __forceinline__ float fexp(float x) {
    float r;
    asm("v_exp_f32 %0, %1" : "=v"(r) : "v"(x * 1.44269504088896f));
    return r;
}
static __device__ __forceinline__ float frcp(float x) {
    float r;
    asm("v_rcp_f32 %0, %1" : "=v"(r) : "v"(x));
    return r;
}

// ---------------------------------------------------------------------------
__global__ void k_detect(const void* __restrict__ g1, int* __restrict__ flag) {
    if (threadIdx.x == 0 && blockIdx.x == 0) {
        const unsigned short* u = (const unsigned short*)g1;
        flag[0] = (u[0] == 0x3F80u) ? 0 : 1;
    }
}

__global__ __launch_bounds__(256) void k_cvt(const void* __restrict__ src,
                                             unsigned short* __restrict__ dst,
                                             int n, const int* __restrict__ flag) {
    int i = blockIdx.x * 256 + threadIdx.x;
    if (i < n) {
        dst[i] = flag[0] ? f2bf(((const float*)src)[i])
                         : ((const unsigned short*)src)[i];
    }
}

// ---------------------------------------------------------------------------
__global__ __launch_bounds__(256) void k_transpose(const void* __restrict__ in,
                                                   unsigned short* __restrict__ out,
                                                   int R, int C, const int* __restrict__ flag) {
    __shared__ unsigned short tile[32][33];
    int isf = flag[0];
    int tx = threadIdx.x, ty = threadIdx.y;
    int x = blockIdx.x * 32 + tx;
    int y0 = blockIdx.y * 32;
    for (int j = ty; j < 32; j += 8) {
        size_t idx = (size_t)(y0 + j) * C + x;
        tile[j][tx] = isf ? f2bf(((const float*)in)[idx]) : ((const unsigned short*)in)[idx];
    }
    __syncthreads();
    int x2 = y0 + tx;
    int y20 = blockIdx.x * 32;
    for (int j = ty; j < 32; j += 8)
        out[(size_t)(y20 + j) * R + x2] = tile[tx][j];
}

// ---------------------------------------------------------------------------
// bias[h][q][k] f32 = bias_table[rel_idx[q,k]][h]
// ---------------------------------------------------------------------------
__global__ __launch_bounds__(256) void k_prep_bias(const void* __restrict__ bias_table,
                                                   const int* __restrict__ rel_idx,
                                                   float* __restrict__ biasp,
                                                   const int* __restrict__ flag) {
    int i = blockIdx.x * 256 + threadIdx.x;   // 65536 total
    int isf = flag[0];
    int h = i & 15, qk = i >> 4;
    size_t idx = (size_t)rel_idx[qk] * 16 + h;
    float v = isf ? ((const float*)bias_table)[idx] : bf2f(((const unsigned short*)bias_table)[idx]);
    biasp[h * 4096 + qk] = v;
}

// ---------------------------------------------------------------------------
__global__ __launch_bounds__(256) void k_partition_ln(const void* __restrict__ x,
                                                      const unsigned short* __restrict__ g1,
                                                      const unsigned short* __restrict__ b1,
                                                      unsigned short* __restrict__ xw,
                                                      unsigned short* __restrict__ h,
                                                      int b0, const int* __restrict__ flag) {
    __shared__ unsigned short tile[64][512];
    int isf = flag[0];
    int bh = blockIdx.x, bl = bh >> 6, hh = bh & 63;
    int b = b0 + bl;
    int tid = threadIdx.x;
    size_t xoff = (((size_t)b * 512) * 64 + hh) * 64;
    int c0 = tid >> 3, ch = tid & 7;
    if (isf) {
        const float* xb = (const float*)x + xoff;
        for (int k = 0; k < 16; ++k) {
            int c = c0 + k * 32;
            f32x4 v0 = *reinterpret_cast<const f32x4*>(xb + (size_t)c * 4096 + ch * 8);
            f32x4 v1 = *reinterpret_cast<const f32x4*>(xb + (size_t)c * 4096 + ch * 8 + 4);
#pragma unroll
            for (int j = 0; j < 4; ++j) tile[ch * 8 + j][c] = f2bf(v0[j]);
#pragma unroll
            for (int j = 0; j < 4; ++j) tile[ch * 8 + 4 + j][c] = f2bf(v1[j]);
        }
    } else {
        const unsigned short* xb = (const unsigned short*)x + xoff;
        for (int k = 0; k < 16; ++k) {
            int c = c0 + k * 32;
            short8 v = *reinterpret_cast<const short8*>(xb + (size_t)c * 4096 + ch * 8);
#pragma unroll
            for (int j = 0; j < 8; ++j) tile[ch * 8 + j][c] = (unsigned short)v[j];
        }
    }
    __syncthreads();
    int w = tid >> 2, q = tid & 3;
    float s = 0.f, s2 = 0.f;
#pragma unroll 4
    for (int j = 0; j < 128; ++j) {
        int c = q * 128 + ((j + 8 * w) & 127);
        float f = bf2f(tile[w][c]);
        s += f; s2 += f * f;
    }
    s += __shfl_xor(s, 1);  s += __shfl_xor(s, 2);
    s2 += __shfl_xor(s2, 1); s2 += __shfl_xor(s2, 2);
    float mu = s * (1.f / 512.f);
    float rstd = rsqrtf(s2 * (1.f / 512.f) - mu * mu + 1e-5f);
    int t = (bl * 64 + (hh >> 3) * 8 + (w >> 3)) * 64 + (hh & 7) * 8 + (w & 7);
    unsigned short* xr = xw + (size_t)t * 512;
    unsigned short* hr = h + (size_t)t * 512;
    for (int cc = q * 128; cc < q * 128 + 128; cc += 8) {
        short8 raw, hn;
#pragma unroll
        for (int j = 0; j < 8; ++j) {
            unsigned short u = tile[w][cc + j];
            raw[j] = (short)u;
            float f = (bf2f(u) - mu) * rstd * bf2f(g1[cc + j]) + bf2f(b1[cc + j]);
            hn[j] = (short)f2bf(f);
        }
        *reinterpret_cast<short8*>(xr + cc) = raw;
        *reinterpret_cast<short8*>(hr + cc) = hn;
    }
}

// ---------------------------------------------------------------------------
__global__ __launch_bounds__(256) void k_ln(const unsigned short* __restrict__ in,
                                            const unsigned short* __restrict__ g,
                                            const unsigned short* __restrict__ b,
                                            unsigned short* __restrict__ out) {
    int wid = threadIdx.x >> 6, lane = threadIdx.x & 63;
    size_t t = (size_t)blockIdx.x * 4 + wid;
    short8 v = *reinterpret_cast<const short8*>(in + t * 512 + lane * 8);
    float f[8], s = 0.f, s2 = 0.f;
#pragma unroll
    for (int j = 0; j < 8; ++j) { f[j] = bf2f((unsigned short)v[j]); s += f[j]; s2 += f[j] * f[j]; }
    for (int m = 1; m < 64; m <<= 1) { s += __shfl_xor(s, m); s2 += __shfl_xor(s2, m); }
    float mu = s * (1.f / 512.f);
    float rstd = rsqrtf(s2 * (1.f / 512.f) - mu * mu + 1e-5f);
    short8 ov;
#pragma unroll
    for (int j = 0; j < 8; ++j)
        ov[j] = (short)f2bf((f[j] - mu) * rstd * bf2f(g[lane * 8 + j]) + bf2f(b[lane * 8 + j]));
    *reinterpret_cast<short8*>(out + t * 512 + lane * 8) = ov;
}

// ---------------------------------------------------------------------------
// GEMM 256x256 (R13 exact: R6 loop + grouped ordering + 16-barrier epilogue).
// Half-K(32) staging into a 4-slot LDS ring (128 KiB), counted vmcnt
// (12/8/4/0), XOR swizzle, setprio, XCD chunking, GROUP_M=8 grouping.
// MODE 0: +bias.  MODE 1: +bias+res.  MODE 2: +bias+GELU.
// Requires nwg % 8 == 0 and gridDim.x % 8 == 0.
// ---------------------------------------------------------------------------
template <int MODE>
__global__ __launch_bounds__(512, 1) void k_gemm14(const unsigned short* __restrict__ A,
                                                   const unsigned short* __restrict__ BT,
                                                   const unsigned short* __restrict__ bias,
                                                   const unsigned short* __restrict__ res,
                                                   unsigned short* __restrict__ out,
                                                   int M, int N, int K) {
    __shared__ unsigned short S[65536];        // 4 slots x (A 8192 + B 8192 elems)
    const int tid = threadIdx.x, lane = tid & 63, wid = tid >> 6;

    int nwg = gridDim.x * gridDim.y;
    int lin = blockIdx.y * gridDim.x + blockIdx.x;
    int swz = (lin & 7) * (nwg >> 3) + (lin >> 3);
    const int G = 8;
    int width = G * gridDim.y;
    int group = swz / width;
    int rem   = swz % width;
    int mt = group * G + (rem % G);
    int nt = rem / G;

    const int wr = wid >> 2, wc = wid & 3;
    const int rl = lane & 15, qg = lane >> 4;

    const int strow = tid >> 2;
    const int scb   = (tid & 3) ^ ((tid >> 3) & 3);
    const unsigned short* Agb = A  + ((size_t)mt * 256 + strow) * K + scb * 8;
    const unsigned short* Bgb = BT + ((size_t)nt * 256 + strow) * K + scb * 8;
    const int ldst = strow * 32 + (tid & 3) * 8;

    f32x4 acc[8][4];
#pragma unroll
    for (int mf = 0; mf < 8; ++mf)
#pragma unroll
        for (int nf = 0; nf < 4; ++nf) {
            acc[mf][nf][0] = 0.f; acc[mf][nf][1] = 0.f; acc[mf][nf][2] = 0.f; acc[mf][nf][3] = 0.f;
        }

    const int NH = K >> 5;

    auto stage = [&](int h) {                  // 4 vmcnt units per call
        int base = (h & 3) * 16384;
#pragma unroll
        for (int s = 0; s < 2; ++s) {
            __builtin_amdgcn_global_load_lds((const gv_void*)(Agb + (size_t)s * 128 * K + h * 32),
                                             (lds_void*)(&S[base + s * 4096 + ldst]), 16, 0, 0);
            __builtin_amdgcn_global_load_lds((const gv_void*)(Bgb + (size_t)s * 128 * K + h * 32),
                                             (lds_void*)(&S[base + 8192 + s * 4096 + ldst]), 16, 0, 0);
        }
    };

    stage(0); stage(1); stage(2);              // 12 loads in flight

    const int arow0 = wr * 128 + rl;
    const int brow0 = wc * 64 + rl;
    const int kbr = (qg ^ ((rl >> 1) & 3)) * 8;

    for (int h = 0; h < NH; ++h) {
        const unsigned short* sA = &S[(h & 3) * 16384];
        const unsigned short* sB = sA + 8192;
        if (h + 3 < NH) {
            stage(h + 3);
            asm volatile("s_waitcnt vmcnt(12)" ::: "memory");
        } else if (h + 2 < NH) {
            asm volatile("s_waitcnt vmcnt(8)" ::: "memory");
        } else if (h + 1 < NH) {
            asm volatile("s_waitcnt vmcnt(4)" ::: "memory");
        } else {
            asm volatile("s_waitcnt vmcnt(0)" ::: "memory");
        }
        __builtin_amdgcn_s_barrier();
        asm volatile("" ::: "memory");

        short8 af[8], bfr[4];
#pragma unroll
        for (int nf = 0; nf < 4; ++nf)
            bfr[nf] = *reinterpret_cast<const short8*>(&sB[(brow0 + nf * 16) * 32 + kbr]);
#pragma unroll
        for (int mf = 0; mf < 8; ++mf)
            af[mf] = *reinterpret_cast<const short8*>(&sA[(arow0 + mf * 16) * 32 + kbr]);

        __builtin_amdgcn_s_setprio(1);
#pragma unroll
        for (int mf = 0; mf < 8; ++mf)
#pragma unroll
            for (int nf = 0; nf < 4; ++nf)
                acc[mf][nf] = __builtin_amdgcn_mfma_f32_16x16x32_bf16(af[mf], bfr[nf], acc[mf][nf], 0, 0, 0);
        __builtin_amdgcn_s_setprio(0);

        __builtin_amdgcn_s_barrier();
        asm volatile("" ::: "memory");
    }

    // ---- epilogue: per-mf LDS bounce, coalesced short8 stores (R13 exact)
    const int PST = 264;
    unsigned short* pb = (unsigned short*)S;
    float bz[4];
#pragma unroll
    for (int nf = 0; nf < 4; ++nf) bz[nf] = bf2f(bias[nt * 256 + wc * 64 + nf * 16 + rl]);
    int row_l = tid >> 4, cbl = (tid & 15) * 16;
    int growb = mt * 256 + (row_l >> 4) * 128 + (row_l & 15);
    size_t gcol = (size_t)nt * 256 + cbl;

#pragma unroll
    for (int mf = 0; mf < 8; ++mf) {
        __syncthreads();
#pragma unroll
        for (int nf = 0; nf < 4; ++nf)
#pragma unroll
            for (int r = 0; r < 4; ++r) {
                float v = acc[mf][nf][r] + bz[nf];
                if (MODE == 2) {
                    float z = 0.7978845608f * (v + 0.044715f * v * v * v);
                    float e = fexp(-2.0f * z);               // gelu = v * sigmoid(2z)
                    v = v * frcp(1.f + e);
                }
                pb[(wr * 16 + qg * 4 + r) * PST + wc * 64 + nf * 16 + rl] = f2bf(v);
            }
        __syncthreads();
        size_t go = (size_t)(growb + mf * 16) * N + gcol;
        short8 o1 = *reinterpret_cast<const short8*>(&pb[row_l * PST + cbl]);
        short8 o2 = *reinterpret_cast<const short8*>(&pb[row_l * PST + cbl + 8]);
        if (MODE == 1) {
            short8 r1 = *reinterpret_cast<const short8*>(&res[go]);
            short8 r2 = *reinterpret_cast<const short8*>(&res[go + 8]);
#pragma unroll
            for (int j = 0; j < 8; ++j) {
                o1[j] = (short)f2bf(bf2f((unsigned short)o1[j]) + bf2f((unsigned short)r1[j]));
                o2[j] = (short)f2bf(bf2f((unsigned short)o2[j]) + bf2f((unsigned short)r2[j]));
            }
        }
        *reinterpret_cast<short8*>(&out[go]) = o1;
        *reinterpret_cast<short8*>(&out[go + 8]) = o2;
    }
}

// ---------------------------------------------------------------------------
// Windowed attention (R6): one wave per (window, head), fast exp/rcp.
// ---------------------------------------------------------------------------
__global__ __launch_bounds__(64) void k_attn(const unsigned short* __restrict__ qkv,
                                             const float* __restrict__ biasp,
                                             unsigned short* __restrict__ o) {
    __shared__ unsigned short Pl[64][72];
    int blk = blockIdx.x;
    int head = blk & 15, win = blk >> 4;
    size_t T0 = (size_t)win * 64;
    int lane = threadIdx.x;
    int rl = lane & 15, qg = lane >> 4;
    const unsigned short* base = qkv + T0 * 1536;
    int qoff = head * 32, koff = 512 + head * 32, voff = 1024 + head * 32;

    f32x4 s[4][4];
#pragma unroll
    for (int m = 0; m < 4; ++m)
#pragma unroll
        for (int n = 0; n < 4; ++n) { s[m][n][0] = 0.f; s[m][n][1] = 0.f; s[m][n][2] = 0.f; s[m][n][3] = 0.f; }

    short8 aq[4], bk[4];
#pragma unroll
    for (int m = 0; m < 4; ++m)
        aq[m] = *reinterpret_cast<const short8*>(base + (size_t)(16 * m + rl) * 1536 + qoff + qg * 8);
#pragma unroll
    for (int n = 0; n < 4; ++n)
        bk[n] = *reinterpret_cast<const short8*>(base + (size_t)(16 * n + rl) * 1536 + koff + qg * 8);
#pragma unroll
    for (int m = 0; m < 4; ++m)
#pragma unroll
        for (int n = 0; n < 4; ++n)
            s[m][n] = __builtin_amdgcn_mfma_f32_16x16x32_bf16(aq[m], bk[n], s[m][n], 0, 0, 0);

    const float scale = 0.17677669529663687f;
    const float* bh = biasp + head * 4096;
#pragma unroll
    for (int m = 0; m < 4; ++m) {
#pragma unroll
        for (int r = 0; r < 4; ++r) {
            int row = 16 * m + qg * 4 + r;
            float v0 = s[m][0][r] * scale + bh[row * 64 + rl];
            float v1 = s[m][1][r] * scale + bh[row * 64 + 16 + rl];
            float v2 = s[m][2][r] * scale + bh[row * 64 + 32 + rl];
            float v3 = s[m][3][r] * scale + bh[row * 64 + 48 + rl];
            float mx = fmaxf(fmaxf(v0, v1), fmaxf(v2, v3));
            mx = fmaxf(mx, __shfl_xor(mx, 1));
            mx = fmaxf(mx, __shfl_xor(mx, 2));
            mx = fmaxf(mx, __shfl_xor(mx, 4));
            mx = fmaxf(mx, __shfl_xor(mx, 8));
            v0 = fexp(v0 - mx); v1 = fexp(v1 - mx); v2 = fexp(v2 - mx); v3 = fexp(v3 - mx);
            float sm = v0 + v1 + v2 + v3;
            sm += __shfl_xor(sm, 1);
            sm += __shfl_xor(sm, 2);
            sm += __shfl_xor(sm, 4);
            sm += __shfl_xor(sm, 8);
            float inv = frcp(sm);
            Pl[row][rl]      = f2bf(v0 * inv);
            Pl[row][16 + rl] = f2bf(v1 * inv);
            Pl[row][32 + rl] = f2bf(v2 * inv);
            Pl[row][48 + rl] = f2bf(v3 * inv);
        }
    }
    __syncthreads();

    short8 bv[2][2];
#pragma unroll
    for (int ks = 0; ks < 2; ++ks)
#pragma unroll
        for (int n2 = 0; n2 < 2; ++n2) {
            short8 t;
#pragma unroll
            for (int i = 0; i < 8; ++i)
                t[i] = (short)base[(size_t)(32 * ks + qg * 8 + i) * 1536 + voff + n2 * 16 + rl];
            bv[ks][n2] = t;
        }

    f32x4 acc2[4][2];
#pragma unroll
    for (int m = 0; m < 4; ++m)
#pragma unroll
        for (int n2 = 0; n2 < 2; ++n2) { acc2[m][n2][0] = 0.f; acc2[m][n2][1] = 0.f; acc2[m][n2][2] = 0.f; acc2[m][n2][3] = 0.f; }

#pragma unroll
    for (int m = 0; m < 4; ++m) {
        short8 p0 = *reinterpret_cast<const short8*>(&Pl[16 * m + rl][qg * 8]);
        short8 p1 = *reinterpret_cast<const short8*>(&Pl[16 * m + rl][32 + qg * 8]);
#pragma unroll
        for (int n2 = 0; n2 < 2; ++n2) {
            acc2[m][n2] = __builtin_amdgcn_mfma_f32_16x16x32_bf16(p0, bv[0][n2], acc2[m][n2], 0, 0, 0);
            acc2[m][n2] = __builtin_amdgcn_mfma_f32_16x16x32_bf16(p1, bv[1][n2], acc2[m][n2], 0, 0, 0);
        }
    }
#pragma unroll
    for (int m = 0; m < 4; ++m)
#pragma unroll
        for (int n2 = 0; n2 < 2; ++n2)
#pragma unroll
            for (int r = 0; r < 4; ++r) {
                int row = 16 * m + qg * 4 + r;
                o[(T0 + row) * 512 + head * 32 + n2 * 16 + rl] = f2bf(acc2[m][n2][r]);
            }
}

// ---------------------------------------------------------------------------
// Window-departition: tokens[t_local][c] -> x[B,C,H,W] (coalesced via LDS)
// ---------------------------------------------------------------------------
__global__ __launch_bounds__(256) void k_departition(const unsigned short* __restrict__ tok,
                                                     void* __restrict__ xo,
                                                     int b0, const int* __restrict__ flag) {
    __shared__ unsigned short tile[64][512];
    int isf = flag[0];
    int bh = blockIdx.x, bl = bh >> 6, hh = bh & 63;
    int b = b0 + bl;
    int tid = threadIdx.x;
    int Tb = (bl * 64 + (hh >> 3) * 8) * 64 + (hh & 7) * 8;
    for (int k = 0; k < 16; ++k) {
        int flat = k * 256 + tid;
        int w = flat >> 6, ch = flat & 63;
        int t = Tb + (w >> 3) * 64 + (w & 7);
        short8 v = *reinterpret_cast<const short8*>(tok + (size_t)t * 512 + ch * 8);
        *reinterpret_cast<short8*>(&tile[w][ch * 8]) = v;
    }
    __syncthreads();
    size_t xoff = (((size_t)b * 512) * 64 + hh) * 64;
    if (isf) {
        float* xb = (float*)xo + xoff;
        for (int k = 0; k < 16; ++k) {
            int flat = k * 256 + tid;
            int c = flat >> 3, wc = flat & 7;
            f32x4 a, d;
#pragma unroll
            for (int j = 0; j < 4; ++j) a[j] = bf2f(tile[wc * 8 + j][c]);
#pragma unroll
            for (int j = 0; j < 4; ++j) d[j] = bf2f(tile[wc * 8 + 4 + j][c]);
            *reinterpret_cast<f32x4*>(xb + (size_t)c * 4096 + wc * 8) = a;
            *reinterpret_cast<f32x4*>(xb + (size_t)c * 4096 + wc * 8 + 4) = d;
        }
    } else {
        unsigned short* xb = (unsigned short*)xo + xoff;
        for (int k = 0; k < 16; ++k) {
            int flat = k * 256 + tid;
            int c = flat >> 3, wc = flat & 7;
            short8 v;
#pragma unroll
            for (int j = 0; j < 8; ++j) v[j] = (short)tile[wc * 8 + j][c];
            *reinterpret_cast<short8*>(xb + (size_t)c * 4096 + wc * 8) = v;
        }
    }
}

// ---------------------------------------------------------------------------
extern "C" void kernel_launch(void* const* d_in, const int* in_sizes, int n_in,
                              void* d_out, int out_size, void* d_ws, size_t ws_size,
                              hipStream_t stream) {
    const void* x          = d_in[0];
    const void* g1         = d_in[1];
    const void* be1        = d_in[2];
    const void* g2         = d_in[3];
    const void* be2        = d_in[4];
    const void* qkv_w      = d_in[5];
    const void* qkv_b      = d_in[6];
    const void* merge_w    = d_in[7];
    const void* merge_b    = d_in[8];
    const void* bias_table = d_in[9];
    const void* w1         = d_in[10];
    const void* b1         = d_in[11];
    const void* w2         = d_in[12];
    const void* b2         = d_in[13];
    const int*  rel_idx    = (const int*)d_in[14];

    // Per-token ws need = 9216 B (xw 1024 + h 1024 + qkv 3072 + mid 4096).
    const size_t extra = 8u << 20;
    int CB = 4;
    if      (ws_size >= (size_t)131072 * 9216 + extra) CB = 32;
    else if (ws_size >= (size_t)65536  * 9216 + extra) CB = 16;
    else if (ws_size >= (size_t)32768  * 9216 + extra) CB = 8;
    int nch = 32 / CB;
    size_t tok = (size_t)CB * 4096;

    unsigned short* xw_c     = (unsigned short*)d_ws;
    unsigned short* h_c      = xw_c + tok * 512;
    unsigned short* qkv_c    = h_c + tok * 512;
    unsigned short* mid_c    = qkv_c + tok * 1536;
    unsigned short* qkv_wT   = mid_c + tok * 2048;
    unsigned short* merge_wT = qkv_wT + 1536 * 512;
    unsigned short* w1T      = merge_wT + 512 * 512;
    unsigned short* w2T      = w1T + 2048 * 512;
    unsigned short* vecs     = w2T + 512 * 2048;
    float*          biasp    = (float*)(vecs + 6656);
    int*            flag     = (int*)(biasp + 65536);

    unsigned short* ng1 = vecs + 0,    *nbe1 = vecs + 512;
    unsigned short* ng2 = vecs + 1024, *nbe2 = vecs + 1536;
    unsigned short* nqb = vecs + 2048, *nmb  = vecs + 3584;
    unsigned short* nb1 = vecs + 4096, *nb2  = vecs + 6144;

    // --- prep
    k_detect<<<1, 64, 0, stream>>>(g1, flag);
    k_cvt<<<2, 256, 0, stream>>>(g1, ng1, 512, flag);
    k_cvt<<<2, 256, 0, stream>>>(be1, nbe1, 512, flag);
    k_cvt<<<2, 256, 0, stream>>>(g2, ng2, 512, flag);
    k_cvt<<<2, 256, 0, stream>>>(be2, nbe2, 512, flag);
    k_cvt<<<6, 256, 0, stream>>>(qkv_b, nqb, 1536, flag);
    k_cvt<<<2, 256, 0, stream>>>(merge_b, nmb, 512, flag);
    k_cvt<<<8, 256, 0, stream>>>(b1, nb1, 2048, flag);
    k_cvt<<<2, 256, 0, stream>>>(b2, nb2, 512, flag);
    k_transpose<<<dim3(48, 16), dim3(32, 8), 0, stream>>>(qkv_w, qkv_wT, 512, 1536, flag);
    k_transpose<<<dim3(16, 16), dim3(32, 8), 0, stream>>>(merge_w, merge_wT, 512, 512, flag);
    k_transpose<<<dim3(64, 16), dim3(32, 8), 0, stream>>>(w1, w1T, 512, 2048, flag);
    k_transpose<<<dim3(16, 64), dim3(32, 8), 0, stream>>>(w2, w2T, 2048, 512, flag);
    k_prep_bias<<<256, 256, 0, stream>>>(bias_table, rel_idx, biasp, flag);

    int mtiles = (int)(tok / 256);
    int M = (int)tok;
    for (int c = 0; c < nch; ++c) {
        int b0 = c * CB;
        k_partition_ln<<<CB * 64, 256, 0, stream>>>(x, ng1, nbe1, xw_c, h_c, b0, flag);
        k_gemm14<0><<<dim3(mtiles, 6), 512, 0, stream>>>(h_c, qkv_wT, nqb, nullptr, qkv_c, M, 1536, 512);
        k_attn<<<CB * 1024, 64, 0, stream>>>(qkv_c, biasp, h_c);            // o -> h_c (h dead)
        k_gemm14<1><<<dim3(mtiles, 2), 512, 0, stream>>>(h_c, merge_wT, nmb, xw_c, xw_c, M, 512, 512);
        k_ln<<<(int)(tok / 4), 256, 0, stream>>>(xw_c, ng2, nbe2, h_c);
        k_gemm14<2><<<dim3(mtiles, 8), 512, 0, stream>>>(h_c, w1T, nb1, nullptr, mid_c, M, 2048, 512);
        k_gemm14<1><<<dim3(mtiles, 2), 512, 0, stream>>>(mid_c, w2T, nb2, xw_c, qkv_c, M, 512, 2048);
        k_departition<<<CB * 64, 256, 0, stream>>>(qkv_c, d_out, b0, flag);
    }
}

// Round 17
// 1769.363 us; speedup vs baseline: 1.1380x; 1.0134x over previous
//
#include <hip/hip_runtime.h>
#include <stdint.h>

typedef __attribute__((ext_vector_type(8))) short short8;
typedef __attribute__((ext_vector_type(4))) float f32x4;
typedef __attribute__((address_space(3))) void lds_void;
typedef __attribute__((address_space(1))) void gv_void;

static __device__ __forceinline__ float bf2f(unsigned short u) {
    union { uint32_t i; float f; } v; v.i = ((uint32_t)u) << 16; return v.f;
}
static __device__ __forceinline__ unsigned short f2bf(float f) {
    union { float f; uint32_t i; } v; v.f = f;
    uint32_t i = v.i;
    uint32_t r = (i + 0x7fffu + ((i >> 16) & 1u)) >> 16;
    return (unsigned short)r;
}
static __device__ __forceinline__ float fexp(float x) {
    float r;
    asm("v_exp_f32 %0, %1" : "=v"(r) : "v"(x * 1.44269504088896f));
    return r;
}
static __device__ __forceinline__ float frcp(float x) {
    float r;
    asm("v_rcp_f32 %0, %1" : "=v"(r) : "v"(x));
    return r;
}

// ---------------------------------------------------------------------------
__global__ void k_detect(const void* __restrict__ g1, int* __restrict__ flag) {
    if (threadIdx.x == 0 && blockIdx.x == 0) {
        const unsigned short* u = (const unsigned short*)g1;
        flag[0] = (u[0] == 0x3F80u) ? 0 : 1;
    }
}

// ---------------------------------------------------------------------------
// All 8 small vectors -> contiguous vecs[6656] in one dispatch.
// Layout: ng1 0 | nbe1 512 | ng2 1024 | nbe2 1536 | nqb 2048 | nmb 3584 |
//         nb1 4096 | nb2 6144 .. 6656
// ---------------------------------------------------------------------------
__global__ __launch_bounds__(256) void k_cvt_all(const void* g1, const void* be1,
                                                 const void* g2, const void* be2,
                                                 const void* qb, const void* mb,
                                                 const void* b1, const void* b2,
                                                 unsigned short* __restrict__ vecs,
                                                 const int* __restrict__ flag) {
    int i = blockIdx.x * 256 + threadIdx.x;
    if (i >= 6656) return;
    const void* src; int off;
    if      (i < 512)  { src = g1;  off = i; }
    else if (i < 1024) { src = be1; off = i - 512; }
    else if (i < 1536) { src = g2;  off = i - 1024; }
    else if (i < 2048) { src = be2; off = i - 1536; }
    else if (i < 3584) { src = qb;  off = i - 2048; }
    else if (i < 4096) { src = mb;  off = i - 3584; }
    else if (i < 6144) { src = b1;  off = i - 4096; }
    else               { src = b2;  off = i - 6144; }
    vecs[i] = flag[0] ? f2bf(((const float*)src)[off])
                      : ((const unsigned short*)src)[off];
}

// ---------------------------------------------------------------------------
// All four weight transposes in one dispatch.  Linear block id ranges:
// [0,768)    qkv_w   [512][1536] -> qkv_wT   (bx=48, by=16)
// [768,1024) merge_w [512][512]  -> merge_wT (bx=16, by=16)
// [1024,2048) w1     [512][2048] -> w1T      (bx=64, by=16)
// [2048,3072) w2     [2048][512] -> w2T      (bx=16, by=64)
// ---------------------------------------------------------------------------
__global__ __launch_bounds__(256) void k_transpose_all(const void* qkv_w, const void* merge_w,
                                                       const void* w1, const void* w2,
                                                       unsigned short* __restrict__ qkv_wT,
                                                       unsigned short* __restrict__ merge_wT,
                                                       unsigned short* __restrict__ w1T,
                                                       unsigned short* __restrict__ w2T,
                                                       const int* __restrict__ flag) {
    __shared__ unsigned short tile[32][33];
    int isf = flag[0];
    int lb = blockIdx.x;
    const void* in; unsigned short* out; int R, C, bx, by;
    if (lb < 768)       { in = qkv_w;   out = qkv_wT;   R = 512;  C = 1536; bx = lb % 48;          by = lb / 48; }
    else if (lb < 1024) { in = merge_w; out = merge_wT; R = 512;  C = 512;  bx = (lb - 768) % 16;  by = (lb - 768) / 16; }
    else if (lb < 2048) { in = w1;      out = w1T;      R = 512;  C = 2048; bx = (lb - 1024) % 64; by = (lb - 1024) / 64; }
    else                { in = w2;      out = w2T;      R = 2048; C = 512;  bx = (lb - 2048) % 16; by = (lb - 2048) / 16; }
    int tx = threadIdx.x & 31, ty = threadIdx.x >> 5;
    int x = bx * 32 + tx;
    int y0 = by * 32;
    for (int j = ty; j < 32; j += 8) {
        size_t idx = (size_t)(y0 + j) * C + x;
        tile[j][tx] = isf ? f2bf(((const float*)in)[idx]) : ((const unsigned short*)in)[idx];
    }
    __syncthreads();
    int x2 = y0 + tx;
    int y20 = bx * 32;
    for (int j = ty; j < 32; j += 8)
        out[(size_t)(y20 + j) * R + x2] = tile[tx][j];
}

// ---------------------------------------------------------------------------
// bias[h][q][k] f32 = bias_table[rel_idx[q,k]][h]
// ---------------------------------------------------------------------------
__global__ __launch_bounds__(256) void k_prep_bias(const void* __restrict__ bias_table,
                                                   const int* __restrict__ rel_idx,
                                                   float* __restrict__ biasp,
                                                   const int* __restrict__ flag) {
    int i = blockIdx.x * 256 + threadIdx.x;   // 65536 total
    int isf = flag[0];
    int h = i & 15, qk = i >> 4;
    size_t idx = (size_t)rel_idx[qk] * 16 + h;
    float v = isf ? ((const float*)bias_table)[idx] : bf2f(((const unsigned short*)bias_table)[idx]);
    biasp[h * 4096 + qk] = v;
}

// ---------------------------------------------------------------------------
__global__ __launch_bounds__(256) void k_partition_ln(const void* __restrict__ x,
                                                      const unsigned short* __restrict__ g1,
                                                      const unsigned short* __restrict__ b1,
                                                      unsigned short* __restrict__ xw,
                                                      unsigned short* __restrict__ h,
                                                      int b0, const int* __restrict__ flag) {
    __shared__ unsigned short tile[64][512];
    int isf = flag[0];
    int bh = blockIdx.x, bl = bh >> 6, hh = bh & 63;
    int b = b0 + bl;
    int tid = threadIdx.x;
    size_t xoff = (((size_t)b * 512) * 64 + hh) * 64;
    int c0 = tid >> 3, ch = tid & 7;
    if (isf) {
        const float* xb = (const float*)x + xoff;
        for (int k = 0; k < 16; ++k) {
            int c = c0 + k * 32;
            f32x4 v0 = *reinterpret_cast<const f32x4*>(xb + (size_t)c * 4096 + ch * 8);
            f32x4 v1 = *reinterpret_cast<const f32x4*>(xb + (size_t)c * 4096 + ch * 8 + 4);
#pragma unroll
            for (int j = 0; j < 4; ++j) tile[ch * 8 + j][c] = f2bf(v0[j]);
#pragma unroll
            for (int j = 0; j < 4; ++j) tile[ch * 8 + 4 + j][c] = f2bf(v1[j]);
        }
    } else {
        const unsigned short* xb = (const unsigned short*)x + xoff;
        for (int k = 0; k < 16; ++k) {
            int c = c0 + k * 32;
            short8 v = *reinterpret_cast<const short8*>(xb + (size_t)c * 4096 + ch * 8);
#pragma unroll
            for (int j = 0; j < 8; ++j) tile[ch * 8 + j][c] = (unsigned short)v[j];
        }
    }
    __syncthreads();
    int w = tid >> 2, q = tid & 3;
    float s = 0.f, s2 = 0.f;
#pragma unroll 4
    for (int j = 0; j < 128; ++j) {
        int c = q * 128 + ((j + 8 * w) & 127);
        float f = bf2f(tile[w][c]);
        s += f; s2 += f * f;
    }
    s += __shfl_xor(s, 1);  s += __shfl_xor(s, 2);
    s2 += __shfl_xor(s2, 1); s2 += __shfl_xor(s2, 2);
    float mu = s * (1.f / 512.f);
    float rstd = rsqrtf(s2 * (1.f / 512.f) - mu * mu + 1e-5f);
    int t = (bl * 64 + (hh >> 3) * 8 + (w >> 3)) * 64 + (hh & 7) * 8 + (w & 7);
    unsigned short* xr = xw + (size_t)t * 512;
    unsigned short* hr = h + (size_t)t * 512;
    for (int cc = q * 128; cc < q * 128 + 128; cc += 8) {
        short8 raw, hn;
#pragma unroll
        for (int j = 0; j < 8; ++j) {
            unsigned short u = tile[w][cc + j];
            raw[j] = (short)u;
            float f = (bf2f(u) - mu) * rstd * bf2f(g1[cc + j]) + bf2f(b1[cc + j]);
            hn[j] = (short)f2bf(f);
        }
        *reinterpret_cast<short8*>(xr + cc) = raw;
        *reinterpret_cast<short8*>(hr + cc) = hn;
    }
}

// ---------------------------------------------------------------------------
__global__ __launch_bounds__(256) void k_ln(const unsigned short* __restrict__ in,
                                            const unsigned short* __restrict__ g,
                                            const unsigned short* __restrict__ b,
                                            unsigned short* __restrict__ out) {
    int wid = threadIdx.x >> 6, lane = threadIdx.x & 63;
    size_t t = (size_t)blockIdx.x * 4 + wid;
    short8 v = *reinterpret_cast<const short8*>(in + t * 512 + lane * 8);
    float f[8], s = 0.f, s2 = 0.f;
#pragma unroll
    for (int j = 0; j < 8; ++j) { f[j] = bf2f((unsigned short)v[j]); s += f[j]; s2 += f[j] * f[j]; }
    for (int m = 1; m < 64; m <<= 1) { s += __shfl_xor(s, m); s2 += __shfl_xor(s2, m); }
    float mu = s * (1.f / 512.f);
    float rstd = rsqrtf(s2 * (1.f / 512.f) - mu * mu + 1e-5f);
    short8 ov;
#pragma unroll
    for (int j = 0; j < 8; ++j)
        ov[j] = (short)f2bf((f[j] - mu) * rstd * bf2f(g[lane * 8 + j]) + bf2f(b[lane * 8 + j]));
    *reinterpret_cast<short8*>(out + t * 512 + lane * 8) = ov;
}

// ---------------------------------------------------------------------------
// GEMM 256x256 (R16 exact): half-K(32) 4-slot LDS ring, counted vmcnt
// (12/8/4/0), XOR swizzle, setprio, XCD chunking, GROUP_M=8 grouping,
// per-mf LDS-bounce epilogue.  MODE 0: +bias. 1: +bias+res. 2: +bias+GELU.
// Requires nwg % 8 == 0 and gridDim.x % 8 == 0.
// ---------------------------------------------------------------------------
template <int MODE>
__global__ __launch_bounds__(512, 1) void k_gemm14(const unsigned short* __restrict__ A,
                                                   const unsigned short* __restrict__ BT,
                                                   const unsigned short* __restrict__ bias,
                                                   const unsigned short* __restrict__ res,
                                                   unsigned short* __restrict__ out,
                                                   int M, int N, int K) {
    __shared__ unsigned short S[65536];        // 4 slots x (A 8192 + B 8192 elems)
    const int tid = threadIdx.x, lane = tid & 63, wid = tid >> 6;

    int nwg = gridDim.x * gridDim.y;
    int lin = blockIdx.y * gridDim.x + blockIdx.x;
    int swz = (lin & 7) * (nwg >> 3) + (lin >> 3);
    const int G = 8;
    int width = G * gridDim.y;
    int group = swz / width;
    int rem   = swz % width;
    int mt = group * G + (rem % G);
    int nt = rem / G;

    const int wr = wid >> 2, wc = wid & 3;
    const int rl = lane & 15, qg = lane >> 4;

    const int strow = tid >> 2;
    const int scb   = (tid & 3) ^ ((tid >> 3) & 3);
    const unsigned short* Agb = A  + ((size_t)mt * 256 + strow) * K + scb * 8;
    const unsigned short* Bgb = BT + ((size_t)nt * 256 + strow) * K + scb * 8;
    const int ldst = strow * 32 + (tid & 3) * 8;

    f32x4 acc[8][4];
#pragma unroll
    for (int mf = 0; mf < 8; ++mf)
#pragma unroll
        for (int nf = 0; nf < 4; ++nf) {
            acc[mf][nf][0] = 0.f; acc[mf][nf][1] = 0.f; acc[mf][nf][2] = 0.f; acc[mf][nf][3] = 0.f;
        }

    const int NH = K >> 5;

    auto stage = [&](int h) {                  // 4 vmcnt units per call
        int base = (h & 3) * 16384;
#pragma unroll
        for (int s = 0; s < 2; ++s) {
            __builtin_amdgcn_global_load_lds((const gv_void*)(Agb + (size_t)s * 128 * K + h * 32),
                                             (lds_void*)(&S[base + s * 4096 + ldst]), 16, 0, 0);
            __builtin_amdgcn_global_load_lds((const gv_void*)(Bgb + (size_t)s * 128 * K + h * 32),
                                             (lds_void*)(&S[base + 8192 + s * 4096 + ldst]), 16, 0, 0);
        }
    };

    stage(0); stage(1); stage(2);              // 12 loads in flight

    const int arow0 = wr * 128 + rl;
    const int brow0 = wc * 64 + rl;
    const int kbr = (qg ^ ((rl >> 1) & 3)) * 8;

    for (int h = 0; h < NH; ++h) {
        const unsigned short* sA = &S[(h & 3) * 16384];
        const unsigned short* sB = sA + 8192;
        if (h + 3 < NH) {
            stage(h + 3);
            asm volatile("s_waitcnt vmcnt(12)" ::: "memory");
        } else if (h + 2 < NH) {
            asm volatile("s_waitcnt vmcnt(8)" ::: "memory");
        } else if (h + 1 < NH) {
            asm volatile("s_waitcnt vmcnt(4)" ::: "memory");
        } else {
            asm volatile("s_waitcnt vmcnt(0)" ::: "memory");
        }
        __builtin_amdgcn_s_barrier();
        asm volatile("" ::: "memory");

        short8 af[8], bfr[4];
#pragma unroll
        for (int nf = 0; nf < 4; ++nf)
            bfr[nf] = *reinterpret_cast<const short8*>(&sB[(brow0 + nf * 16) * 32 + kbr]);
#pragma unroll
        for (int mf = 0; mf < 8; ++mf)
            af[mf] = *reinterpret_cast<const short8*>(&sA[(arow0 + mf * 16) * 32 + kbr]);

        __builtin_amdgcn_s_setprio(1);
#pragma unroll
        for (int mf = 0; mf < 8; ++mf)
#pragma unroll
            for (int nf = 0; nf < 4; ++nf)
                acc[mf][nf] = __builtin_amdgcn_mfma_f32_16x16x32_bf16(af[mf], bfr[nf], acc[mf][nf], 0, 0, 0);
        __builtin_amdgcn_s_setprio(0);

        __builtin_amdgcn_s_barrier();
        asm volatile("" ::: "memory");
    }

    // ---- epilogue: per-mf LDS bounce, coalesced short8 stores
    const int PST = 264;
    unsigned short* pb = (unsigned short*)S;
    float bz[4];
#pragma unroll
    for (int nf = 0; nf < 4; ++nf) bz[nf] = bf2f(bias[nt * 256 + wc * 64 + nf * 16 + rl]);
    int row_l = tid >> 4, cbl = (tid & 15) * 16;
    int growb = mt * 256 + (row_l >> 4) * 128 + (row_l & 15);
    size_t gcol = (size_t)nt * 256 + cbl;

#pragma unroll
    for (int mf = 0; mf < 8; ++mf) {
        __syncthreads();
#pragma unroll
        for (int nf = 0; nf < 4; ++nf)
#pragma unroll
            for (int r = 0; r < 4; ++r) {
                float v = acc[mf][nf][r] + bz[nf];
                if (MODE == 2) {
                    float z = 0.7978845608f * (v + 0.044715f * v * v * v);
                    float e = fexp(-2.0f * z);               // gelu = v * sigmoid(2z)
                    v = v * frcp(1.f + e);
                }
                pb[(wr * 16 + qg * 4 + r) * PST + wc * 64 + nf * 16 + rl] = f2bf(v);
            }
        __syncthreads();
        size_t go = (size_t)(growb + mf * 16) * N + gcol;
        short8 o1 = *reinterpret_cast<const short8*>(&pb[row_l * PST + cbl]);
        short8 o2 = *reinterpret_cast<const short8*>(&pb[row_l * PST + cbl + 8]);
        if (MODE == 1) {
            short8 r1 = *reinterpret_cast<const short8*>(&res[go]);
            short8 r2 = *reinterpret_cast<const short8*>(&res[go + 8]);
#pragma unroll
            for (int j = 0; j < 8; ++j) {
                o1[j] = (short)f2bf(bf2f((unsigned short)o1[j]) + bf2f((unsigned short)r1[j]));
                o2[j] = (short)f2bf(bf2f((unsigned short)o2[j]) + bf2f((unsigned short)r2[j]));
            }
        }
        *reinterpret_cast<short8*>(&out[go]) = o1;
        *reinterpret_cast<short8*>(&out[go + 8]) = o2;
    }
}

// ---------------------------------------------------------------------------
// Windowed attention (R6): one wave per (window, head), fast exp/rcp.
// ---------------------------------------------------------------------------
__global__ __launch_bounds__(64) void k_attn(const unsigned short* __restrict__ qkv,
                                             const float* __restrict__ biasp,
                                             unsigned short* __restrict__ o) {
    __shared__ unsigned short Pl[64][72];
    int blk = blockIdx.x;
    int head = blk & 15, win = blk >> 4;
    size_t T0 = (size_t)win * 64;
    int lane = threadIdx.x;
    int rl = lane & 15, qg = lane >> 4;
    const unsigned short* base = qkv + T0 * 1536;
    int qoff = head * 32, koff = 512 + head * 32, voff = 1024 + head * 32;

    f32x4 s[4][4];
#pragma unroll
    for (int m = 0; m < 4; ++m)
#pragma unroll
        for (int n = 0; n < 4; ++n) { s[m][n][0] = 0.f; s[m][n][1] = 0.f; s[m][n][2] = 0.f; s[m][n][3] = 0.f; }

    short8 aq[4], bk[4];
#pragma unroll
    for (int m = 0; m < 4; ++m)
        aq[m] = *reinterpret_cast<const short8*>(base + (size_t)(16 * m + rl) * 1536 + qoff + qg * 8);
#pragma unroll
    for (int n = 0; n < 4; ++n)
        bk[n] = *reinterpret_cast<const short8*>(base + (size_t)(16 * n + rl) * 1536 + koff + qg * 8);
#pragma unroll
    for (int m = 0; m < 4; ++m)
#pragma unroll
        for (int n = 0; n < 4; ++n)
            s[m][n] = __builtin_amdgcn_mfma_f32_16x16x32_bf16(aq[m], bk[n], s[m][n], 0, 0, 0);

    const float scale = 0.17677669529663687f;
    const float* bh = biasp + head * 4096;
#pragma unroll
    for (int m = 0; m < 4; ++m) {
#pragma unroll
        for (int r = 0; r < 4; ++r) {
            int row = 16 * m + qg * 4 + r;
            float v0 = s[m][0][r] * scale + bh[row * 64 + rl];
            float v1 = s[m][1][r] * scale + bh[row * 64 + 16 + rl];
            float v2 = s[m][2][r] * scale + bh[row * 64 + 32 + rl];
            float v3 = s[m][3][r] * scale + bh[row * 64 + 48 + rl];
            float mx = fmaxf(fmaxf(v0, v1), fmaxf(v2, v3));
            mx = fmaxf(mx, __shfl_xor(mx, 1));
            mx = fmaxf(mx, __shfl_xor(mx, 2));
            mx = fmaxf(mx, __shfl_xor(mx, 4));
            mx = fmaxf(mx, __shfl_xor(mx, 8));
            v0 = fexp(v0 - mx); v1 = fexp(v1 - mx); v2 = fexp(v2 - mx); v3 = fexp(v3 - mx);
            float sm = v0 + v1 + v2 + v3;
            sm += __shfl_xor(sm, 1);
            sm += __shfl_xor(sm, 2);
            sm += __shfl_xor(sm, 4);
            sm += __shfl_xor(sm, 8);
            float inv = frcp(sm);
            Pl[row][rl]      = f2bf(v0 * inv);
            Pl[row][16 + rl] = f2bf(v1 * inv);
            Pl[row][32 + rl] = f2bf(v2 * inv);
            Pl[row][48 + rl] = f2bf(v3 * inv);
        }
    }
    __syncthreads();

    short8 bv[2][2];
#pragma unroll
    for (int ks = 0; ks < 2; ++ks)
#pragma unroll
        for (int n2 = 0; n2 < 2; ++n2) {
            short8 t;
#pragma unroll
            for (int i = 0; i < 8; ++i)
                t[i] = (short)base[(size_t)(32 * ks + qg * 8 + i) * 1536 + voff + n2 * 16 + rl];
            bv[ks][n2] = t;
        }

    f32x4 acc2[4][2];
#pragma unroll
    for (int m = 0; m < 4; ++m)
#pragma unroll
        for (int n2 = 0; n2 < 2; ++n2) { acc2[m][n2][0] = 0.f; acc2[m][n2][1] = 0.f; acc2[m][n2][2] = 0.f; acc2[m][n2][3] = 0.f; }

#pragma unroll
    for (int m = 0; m < 4; ++m) {
        short8 p0 = *reinterpret_cast<const short8*>(&Pl[16 * m + rl][qg * 8]);
        short8 p1 = *reinterpret_cast<const short8*>(&Pl[16 * m + rl][32 + qg * 8]);
#pragma unroll
        for (int n2 = 0; n2 < 2; ++n2) {
            acc2[m][n2] = __builtin_amdgcn_mfma_f32_16x16x32_bf16(p0, bv[0][n2], acc2[m][n2], 0, 0, 0);
            acc2[m][n2] = __builtin_amdgcn_mfma_f32_16x16x32_bf16(p1, bv[1][n2], acc2[m][n2], 0, 0, 0);
        }
    }
#pragma unroll
    for (int m = 0; m < 4; ++m)
#pragma unroll
        for (int n2 = 0; n2 < 2; ++n2)
#pragma unroll
            for (int r = 0; r < 4; ++r) {
                int row = 16 * m + qg * 4 + r;
                o[(T0 + row) * 512 + head * 32 + n2 * 16 + rl] = f2bf(acc2[m][n2][r]);
            }
}

// ---------------------------------------------------------------------------
// Window-departition: tokens[t_local][c] -> x[B,C,H,W] (coalesced via LDS)
// ---------------------------------------------------------------------------
__global__ __launch_bounds__(256) void k_departition(const unsigned short* __restrict__ tok,
                                                     void* __restrict__ xo,
                                                     int b0, const int* __restrict__ flag) {
    __shared__ unsigned short tile[64][512];
    int isf = flag[0];
    int bh = blockIdx.x, bl = bh >> 6, hh = bh & 63;
    int b = b0 + bl;
    int tid = threadIdx.x;
    int Tb = (bl * 64 + (hh >> 3) * 8) * 64 + (hh & 7) * 8;
    for (int k = 0; k < 16; ++k) {
        int flat = k * 256 + tid;
        int w = flat >> 6, ch = flat & 63;
        int t = Tb + (w >> 3) * 64 + (w & 7);
        short8 v = *reinterpret_cast<const short8*>(tok + (size_t)t * 512 + ch * 8);
        *reinterpret_cast<short8*>(&tile[w][ch * 8]) = v;
    }
    __syncthreads();
    size_t xoff = (((size_t)b * 512) * 64 + hh) * 64;
    if (isf) {
        float* xb = (float*)xo + xoff;
        for (int k = 0; k < 16; ++k) {
            int flat = k * 256 + tid;
            int c = flat >> 3, wc = flat & 7;
            f32x4 a, d;
#pragma unroll
            for (int j = 0; j < 4; ++j) a[j] = bf2f(tile[wc * 8 + j][c]);
#pragma unroll
            for (int j = 0; j < 4; ++j) d[j] = bf2f(tile[wc * 8 + 4 + j][c]);
            *reinterpret_cast<f32x4*>(xb + (size_t)c * 4096 + wc * 8) = a;
            *reinterpret_cast<f32x4*>(xb + (size_t)c * 4096 + wc * 8 + 4) = d;
        }
    } else {
        unsigned short* xb = (unsigned short*)xo + xoff;
        for (int k = 0; k < 16; ++k) {
            int flat = k * 256 + tid;
            int c = flat >> 3, wc = flat & 7;
            short8 v;
#pragma unroll
            for (int j = 0; j < 8; ++j) v[j] = (short)tile[wc * 8 + j][c];
            *reinterpret_cast<short8*>(xb + (size_t)c * 4096 + wc * 8) = v;
        }
    }
}

// ---------------------------------------------------------------------------
extern "C" void kernel_launch(void* const* d_in, const int* in_sizes, int n_in,
                              void* d_out, int out_size, void* d_ws, size_t ws_size,
                              hipStream_t stream) {
    const void* x          = d_in[0];
    const void* g1         = d_in[1];
    const void* be1        = d_in[2];
    const void* g2         = d_in[3];
    const void* be2        = d_in[4];
    const void* qkv_w      = d_in[5];
    const void* qkv_b      = d_in[6];
    const void* merge_w    = d_in[7];
    const void* merge_b    = d_in[8];
    const void* bias_table = d_in[9];
    const void* w1         = d_in[10];
    const void* b1         = d_in[11];
    const void* w2         = d_in[12];
    const void* b2         = d_in[13];
    const int*  rel_idx    = (const int*)d_in[14];

    // Per-token ws need = 9216 B (xw 1024 + h 1024 + qkv 3072 + mid 4096).
    const size_t extra = 8u << 20;
    int CB = 4;
    if      (ws_size >= (size_t)131072 * 9216 + extra) CB = 32;
    else if (ws_size >= (size_t)65536  * 9216 + extra) CB = 16;
    else if (ws_size >= (size_t)32768  * 9216 + extra) CB = 8;
    int nch = 32 / CB;
    size_t tok = (size_t)CB * 4096;

    unsigned short* xw_c     = (unsigned short*)d_ws;
    unsigned short* h_c      = xw_c + tok * 512;
    unsigned short* qkv_c    = h_c + tok * 512;
    unsigned short* mid_c    = qkv_c + tok * 1536;
    unsigned short* qkv_wT   = mid_c + tok * 2048;
    unsigned short* merge_wT = qkv_wT + 1536 * 512;
    unsigned short* w1T      = merge_wT + 512 * 512;
    unsigned short* w2T      = w1T + 2048 * 512;
    unsigned short* vecs     = w2T + 512 * 2048;
    float*          biasp    = (float*)(vecs + 6656);
    int*            flag     = (int*)(biasp + 65536);

    unsigned short* ng1 = vecs + 0,    *nbe1 = vecs + 512;
    unsigned short* ng2 = vecs + 1024, *nbe2 = vecs + 1536;
    unsigned short* nqb = vecs + 2048, *nmb  = vecs + 3584;
    unsigned short* nb1 = vecs + 4096, *nb2  = vecs + 6144;

    // --- prep (4 dispatches)
    k_detect<<<1, 64, 0, stream>>>(g1, flag);
    k_cvt_all<<<26, 256, 0, stream>>>(g1, be1, g2, be2, qkv_b, merge_b, b1, b2, vecs, flag);
    k_transpose_all<<<3072, 256, 0, stream>>>(qkv_w, merge_w, w1, w2,
                                              qkv_wT, merge_wT, w1T, w2T, flag);
    k_prep_bias<<<256, 256, 0, stream>>>(bias_table, rel_idx, biasp, flag);

    int mtiles = (int)(tok / 256);
    int M = (int)tok;
    for (int c = 0; c < nch; ++c) {
        int b0 = c * CB;
        k_partition_ln<<<CB * 64, 256, 0, stream>>>(x, ng1, nbe1, xw_c, h_c, b0, flag);
        k_gemm14<0><<<dim3(mtiles, 6), 512, 0, stream>>>(h_c, qkv_wT, nqb, nullptr, qkv_c, M, 1536, 512);
        k_attn<<<CB * 1024, 64, 0, stream>>>(qkv_c, biasp, h_c);            // o -> h_c (h dead)
        k_gemm14<1><<<dim3(mtiles, 2), 512, 0, stream>>>(h_c, merge_wT, nmb, xw_c, xw_c, M, 512, 512);
        k_ln<<<(int)(tok / 4), 256, 0, stream>>>(xw_c, ng2, nbe2, h_c);
        k_gemm14<2><<<dim3(mtiles, 8), 512, 0, stream>>>(h_c, w1T, nb1, nullptr, mid_c, M, 2048, 512);
        k_gemm14<1><<<dim3(mtiles, 2), 512, 0, stream>>>(mid_c, w2T, nb2, xw_c, qkv_c, M, 512, 2048);
        k_departition<<<CB * 64, 256, 0, stream>>>(qkv_c, d_out, b0, flag);
    }
}

// Round 18
// 1756.841 us; speedup vs baseline: 1.1461x; 1.0071x over previous
//
#include <hip/hip_runtime.h>
#include <stdint.h>

typedef __attribute__((ext_vector_type(8))) short short8;
typedef __attribute__((ext_vector_type(4))) float f32x4;
typedef __attribute__((address_space(3))) void lds_void;
typedef __attribute__((address_space(1))) void gv_void;

static __device__ __forceinline__ float bf2f(unsigned short u) {
    union { uint32_t i; float f; } v; v.i = ((uint32_t)u) << 16; return v.f;
}
static __device__ __forceinline__ unsigned short f2bf(float f) {
    union { float f; uint32_t i; } v; v.f = f;
    uint32_t i = v.i;
    uint32_t r = (i + 0x7fffu + ((i >> 16) & 1u)) >> 16;
    return (unsigned short)r;
}
static __device__ __forceinline__ float fexp(float x) {
    float r;
    asm("v_exp_f32 %0, %1" : "=v"(r) : "v"(x * 1.44269504088896f));
    return r;
}
static __device__ __forceinline__ float frcp(float x) {
    float r;
    asm("v_rcp_f32 %0, %1" : "=v"(r) : "v"(x));
    return r;
}

// ---------------------------------------------------------------------------
__global__ void k_detect(const void* __restrict__ g1, int* __restrict__ flag) {
    if (threadIdx.x == 0 && blockIdx.x == 0) {
        const unsigned short* u = (const unsigned short*)g1;
        flag[0] = (u[0] == 0x3F80u) ? 0 : 1;
    }
}

// ---------------------------------------------------------------------------
// All 8 small vectors -> contiguous vecs[6656] in one dispatch.
// ---------------------------------------------------------------------------
__global__ __launch_bounds__(256) void k_cvt_all(const void* g1, const void* be1,
                                                 const void* g2, const void* be2,
                                                 const void* qb, const void* mb,
                                                 const void* b1, const void* b2,
                                                 unsigned short* __restrict__ vecs,
                                                 const int* __restrict__ flag) {
    int i = blockIdx.x * 256 + threadIdx.x;
    if (i >= 6656) return;
    const void* src; int off;
    if      (i < 512)  { src = g1;  off = i; }
    else if (i < 1024) { src = be1; off = i - 512; }
    else if (i < 1536) { src = g2;  off = i - 1024; }
    else if (i < 2048) { src = be2; off = i - 1536; }
    else if (i < 3584) { src = qb;  off = i - 2048; }
    else if (i < 4096) { src = mb;  off = i - 3584; }
    else if (i < 6144) { src = b1;  off = i - 4096; }
    else               { src = b2;  off = i - 6144; }
    vecs[i] = flag[0] ? f2bf(((const float*)src)[off])
                      : ((const unsigned short*)src)[off];
}

// ---------------------------------------------------------------------------
// All four weight transposes in one dispatch.
// ---------------------------------------------------------------------------
__global__ __launch_bounds__(256) void k_transpose_all(const void* qkv_w, const void* merge_w,
                                                       const void* w1, const void* w2,
                                                       unsigned short* __restrict__ qkv_wT,
                                                       unsigned short* __restrict__ merge_wT,
                                                       unsigned short* __restrict__ w1T,
                                                       unsigned short* __restrict__ w2T,
                                                       const int* __restrict__ flag) {
    __shared__ unsigned short tile[32][33];
    int isf = flag[0];
    int lb = blockIdx.x;
    const void* in; unsigned short* out; int R, C, bx, by;
    if (lb < 768)       { in = qkv_w;   out = qkv_wT;   R = 512;  C = 1536; bx = lb % 48;          by = lb / 48; }
    else if (lb < 1024) { in = merge_w; out = merge_wT; R = 512;  C = 512;  bx = (lb - 768) % 16;  by = (lb - 768) / 16; }
    else if (lb < 2048) { in = w1;      out = w1T;      R = 512;  C = 2048; bx = (lb - 1024) % 64; by = (lb - 1024) / 64; }
    else                { in = w2;      out = w2T;      R = 2048; C = 512;  bx = (lb - 2048) % 16; by = (lb - 2048) / 16; }
    int tx = threadIdx.x & 31, ty = threadIdx.x >> 5;
    int x = bx * 32 + tx;
    int y0 = by * 32;
    for (int j = ty; j < 32; j += 8) {
        size_t idx = (size_t)(y0 + j) * C + x;
        tile[j][tx] = isf ? f2bf(((const float*)in)[idx]) : ((const unsigned short*)in)[idx];
    }
    __syncthreads();
    int x2 = y0 + tx;
    int y20 = bx * 32;
    for (int j = ty; j < 32; j += 8)
        out[(size_t)(y20 + j) * R + x2] = tile[tx][j];
}

// ---------------------------------------------------------------------------
// bias[h][q][k] f32 = bias_table[rel_idx[q,k]][h]
// ---------------------------------------------------------------------------
__global__ __launch_bounds__(256) void k_prep_bias(const void* __restrict__ bias_table,
                                                   const int* __restrict__ rel_idx,
                                                   float* __restrict__ biasp,
                                                   const int* __restrict__ flag) {
    int i = blockIdx.x * 256 + threadIdx.x;   // 65536 total
    int isf = flag[0];
    int h = i & 15, qk = i >> 4;
    size_t idx = (size_t)rel_idx[qk] * 16 + h;
    float v = isf ? ((const float*)bias_table)[idx] : bf2f(((const unsigned short*)bias_table)[idx]);
    biasp[h * 4096 + qk] = v;
}

// ---------------------------------------------------------------------------
__global__ __launch_bounds__(256) void k_partition_ln(const void* __restrict__ x,
                                                      const unsigned short* __restrict__ g1,
                                                      const unsigned short* __restrict__ b1,
                                                      unsigned short* __restrict__ xw,
                                                      unsigned short* __restrict__ h,
                                                      int b0, const int* __restrict__ flag) {
    __shared__ unsigned short tile[64][512];
    int isf = flag[0];
    int bh = blockIdx.x, bl = bh >> 6, hh = bh & 63;
    int b = b0 + bl;
    int tid = threadIdx.x;
    size_t xoff = (((size_t)b * 512) * 64 + hh) * 64;
    int c0 = tid >> 3, ch = tid & 7;
    if (isf) {
        const float* xb = (const float*)x + xoff;
        for (int k = 0; k < 16; ++k) {
            int c = c0 + k * 32;
            f32x4 v0 = *reinterpret_cast<const f32x4*>(xb + (size_t)c * 4096 + ch * 8);
            f32x4 v1 = *reinterpret_cast<const f32x4*>(xb + (size_t)c * 4096 + ch * 8 + 4);
#pragma unroll
            for (int j = 0; j < 4; ++j) tile[ch * 8 + j][c] = f2bf(v0[j]);
#pragma unroll
            for (int j = 0; j < 4; ++j) tile[ch * 8 + 4 + j][c] = f2bf(v1[j]);
        }
    } else {
        const unsigned short* xb = (const unsigned short*)x + xoff;
        for (int k = 0; k < 16; ++k) {
            int c = c0 + k * 32;
            short8 v = *reinterpret_cast<const short8*>(xb + (size_t)c * 4096 + ch * 8);
#pragma unroll
            for (int j = 0; j < 8; ++j) tile[ch * 8 + j][c] = (unsigned short)v[j];
        }
    }
    __syncthreads();
    int w = tid >> 2, q = tid & 3;
    float s = 0.f, s2 = 0.f;
#pragma unroll 4
    for (int j = 0; j < 128; ++j) {
        int c = q * 128 + ((j + 8 * w) & 127);
        float f = bf2f(tile[w][c]);
        s += f; s2 += f * f;
    }
    s += __shfl_xor(s, 1);  s += __shfl_xor(s, 2);
    s2 += __shfl_xor(s2, 1); s2 += __shfl_xor(s2, 2);
    float mu = s * (1.f / 512.f);
    float rstd = rsqrtf(s2 * (1.f / 512.f) - mu * mu + 1e-5f);
    int t = (bl * 64 + (hh >> 3) * 8 + (w >> 3)) * 64 + (hh & 7) * 8 + (w & 7);
    unsigned short* xr = xw + (size_t)t * 512;
    unsigned short* hr = h + (size_t)t * 512;
    for (int cc = q * 128; cc < q * 128 + 128; cc += 8) {
        short8 raw, hn;
#pragma unroll
        for (int j = 0; j < 8; ++j) {
            unsigned short u = tile[w][cc + j];
            raw[j] = (short)u;
            float f = (bf2f(u) - mu) * rstd * bf2f(g1[cc + j]) + bf2f(b1[cc + j]);
            hn[j] = (short)f2bf(f);
        }
        *reinterpret_cast<short8*>(xr + cc) = raw;
        *reinterpret_cast<short8*>(hr + cc) = hn;
    }
}

// ---------------------------------------------------------------------------
__global__ __launch_bounds__(256) void k_ln(const unsigned short* __restrict__ in,
                                            const unsigned short* __restrict__ g,
                                            const unsigned short* __restrict__ b,
                                            unsigned short* __restrict__ out) {
    int wid = threadIdx.x >> 6, lane = threadIdx.x & 63;
    size_t t = (size_t)blockIdx.x * 4 + wid;
    short8 v = *reinterpret_cast<const short8*>(in + t * 512 + lane * 8);
    float f[8], s = 0.f, s2 = 0.f;
#pragma unroll
    for (int j = 0; j < 8; ++j) { f[j] = bf2f((unsigned short)v[j]); s += f[j]; s2 += f[j] * f[j]; }
    for (int m = 1; m < 64; m <<= 1) { s += __shfl_xor(s, m); s2 += __shfl_xor(s2, m); }
    float mu = s * (1.f / 512.f);
    float rstd = rsqrtf(s2 * (1.f / 512.f) - mu * mu + 1e-5f);
    short8 ov;
#pragma unroll
    for (int j = 0; j < 8; ++j)
        ov[j] = (short)f2bf((f[j] - mu) * rstd * bf2f(g[lane * 8 + j]) + bf2f(b[lane * 8 + j]));
    *reinterpret_cast<short8*>(out + t * 512 + lane * 8) = ov;
}

// ---------------------------------------------------------------------------
// GEMM 256x256, 2-slot LDS ring (64 KiB -> 2 blocks/CU cross-block overlap,
// m114 mechanism), counted vmcnt(4/0), XOR swizzle, setprio, XCD chunking,
// GROUP_M=8 grouping, per-mf LDS-bounce epilogue.  Race-free slot reuse:
// vmcnt -> barrier -> ds_read -> MFMA (lgkm-waited) -> barrier -> stage(h+2).
// MODE 0: +bias.  MODE 1: +bias+res.  MODE 2: +bias+GELU.
// Requires nwg % 8 == 0 and gridDim.x % 8 == 0.
// ---------------------------------------------------------------------------
template <int MODE>
__global__ __launch_bounds__(512, 1) void k_gemm18(const unsigned short* __restrict__ A,
                                                   const unsigned short* __restrict__ BT,
                                                   const unsigned short* __restrict__ bias,
                                                   const unsigned short* __restrict__ res,
                                                   unsigned short* __restrict__ out,
                                                   int M, int N, int K) {
    __shared__ unsigned short S[32768];        // 2 slots x (A 8192 + B 8192 elems) = 64 KiB
    const int tid = threadIdx.x, lane = tid & 63, wid = tid >> 6;

    int nwg = gridDim.x * gridDim.y;
    int lin = blockIdx.y * gridDim.x + blockIdx.x;
    int swz = (lin & 7) * (nwg >> 3) + (lin >> 3);
    const int G = 8;
    int width = G * gridDim.y;
    int group = swz / width;
    int rem   = swz % width;
    int mt = group * G + (rem % G);
    int nt = rem / G;

    const int wr = wid >> 2, wc = wid & 3;
    const int rl = lane & 15, qg = lane >> 4;

    const int strow = tid >> 2;
    const int scb   = (tid & 3) ^ ((tid >> 3) & 3);
    const unsigned short* Agb = A  + ((size_t)mt * 256 + strow) * K + scb * 8;
    const unsigned short* Bgb = BT + ((size_t)nt * 256 + strow) * K + scb * 8;
    const int ldst = strow * 32 + (tid & 3) * 8;

    f32x4 acc[8][4];
#pragma unroll
    for (int mf = 0; mf < 8; ++mf)
#pragma unroll
        for (int nf = 0; nf < 4; ++nf) {
            acc[mf][nf][0] = 0.f; acc[mf][nf][1] = 0.f; acc[mf][nf][2] = 0.f; acc[mf][nf][3] = 0.f;
        }

    const int NH = K >> 5;

    auto stage = [&](int h) {                  // 4 vmcnt units per call
        int base = (h & 1) * 16384;
#pragma unroll
        for (int s = 0; s < 2; ++s) {
            __builtin_amdgcn_global_load_lds((const gv_void*)(Agb + (size_t)s * 128 * K + h * 32),
                                             (lds_void*)(&S[base + s * 4096 + ldst]), 16, 0, 0);
            __builtin_amdgcn_global_load_lds((const gv_void*)(Bgb + (size_t)s * 128 * K + h * 32),
                                             (lds_void*)(&S[base + 8192 + s * 4096 + ldst]), 16, 0, 0);
        }
    };

    stage(0); stage(1);                        // 8 loads in flight

    const int arow0 = wr * 128 + rl;
    const int brow0 = wc * 64 + rl;
    const int kbr = (qg ^ ((rl >> 1) & 3)) * 8;

    for (int h = 0; h < NH; ++h) {
        const unsigned short* sA = &S[(h & 1) * 16384];
        const unsigned short* sB = sA + 8192;
        if (h + 1 < NH) {
            asm volatile("s_waitcnt vmcnt(4)" ::: "memory");   // slot h landed
        } else {
            asm volatile("s_waitcnt vmcnt(0)" ::: "memory");
        }
        __builtin_amdgcn_s_barrier();
        asm volatile("" ::: "memory");

        short8 af[8], bfr[4];
#pragma unroll
        for (int nf = 0; nf < 4; ++nf)
            bfr[nf] = *reinterpret_cast<const short8*>(&sB[(brow0 + nf * 16) * 32 + kbr]);
#pragma unroll
        for (int mf = 0; mf < 8; ++mf)
            af[mf] = *reinterpret_cast<const short8*>(&sA[(arow0 + mf * 16) * 32 + kbr]);

        __builtin_amdgcn_s_setprio(1);
#pragma unroll
        for (int mf = 0; mf < 8; ++mf)
#pragma unroll
            for (int nf = 0; nf < 4; ++nf)
                acc[mf][nf] = __builtin_amdgcn_mfma_f32_16x16x32_bf16(af[mf], bfr[nf], acc[mf][nf], 0, 0, 0);
        __builtin_amdgcn_s_setprio(0);

        __builtin_amdgcn_s_barrier();          // all waves' reads of slot h complete
        asm volatile("" ::: "memory");
        if (h + 2 < NH) stage(h + 2);          // safe slot overwrite
    }

    // ---- epilogue: per-mf LDS bounce, coalesced short8 stores
    const int PST = 264;
    unsigned short* pb = (unsigned short*)S;
    float bz[4];
#pragma unroll
    for (int nf = 0; nf < 4; ++nf) bz[nf] = bf2f(bias[nt * 256 + wc * 64 + nf * 16 + rl]);
    int row_l = tid >> 4, cbl = (tid & 15) * 16;
    int growb = mt * 256 + (row_l >> 4) * 128 + (row_l & 15);
    size_t gcol = (size_t)nt * 256 + cbl;

#pragma unroll
    for (int mf = 0; mf < 8; ++mf) {
        __syncthreads();
#pragma unroll
        for (int nf = 0; nf < 4; ++nf)
#pragma unroll
            for (int r = 0; r < 4; ++r) {
                float v = acc[mf][nf][r] + bz[nf];
                if (MODE == 2) {
                    float z = 0.7978845608f * (v + 0.044715f * v * v * v);
                    float e = fexp(-2.0f * z);               // gelu = v * sigmoid(2z)
                    v = v * frcp(1.f + e);
                }
                pb[(wr * 16 + qg * 4 + r) * PST + wc * 64 + nf * 16 + rl] = f2bf(v);
            }
        __syncthreads();
        size_t go = (size_t)(growb + mf * 16) * N + gcol;
        short8 o1 = *reinterpret_cast<const short8*>(&pb[row_l * PST + cbl]);
        short8 o2 = *reinterpret_cast<const short8*>(&pb[row_l * PST + cbl + 8]);
        if (MODE == 1) {
            short8 r1 = *reinterpret_cast<const short8*>(&res[go]);
            short8 r2 = *reinterpret_cast<const short8*>(&res[go + 8]);
#pragma unroll
            for (int j = 0; j < 8; ++j) {
                o1[j] = (short)f2bf(bf2f((unsigned short)o1[j]) + bf2f((unsigned short)r1[j]));
                o2[j] = (short)f2bf(bf2f((unsigned short)o2[j]) + bf2f((unsigned short)r2[j]));
            }
        }
        *reinterpret_cast<short8*>(&out[go]) = o1;
        *reinterpret_cast<short8*>(&out[go + 8]) = o2;
    }
}

// ---------------------------------------------------------------------------
// Windowed attention (R6): one wave per (window, head), fast exp/rcp.
// ---------------------------------------------------------------------------
__global__ __launch_bounds__(64) void k_attn(const unsigned short* __restrict__ qkv,
                                             const float* __restrict__ biasp,
                                             unsigned short* __restrict__ o) {
    __shared__ unsigned short Pl[64][72];
    int blk = blockIdx.x;
    int head = blk & 15, win = blk >> 4;
    size_t T0 = (size_t)win * 64;
    int lane = threadIdx.x;
    int rl = lane & 15, qg = lane >> 4;
    const unsigned short* base = qkv + T0 * 1536;
    int qoff = head * 32, koff = 512 + head * 32, voff = 1024 + head * 32;

    f32x4 s[4][4];
#pragma unroll
    for (int m = 0; m < 4; ++m)
#pragma unroll
        for (int n = 0; n < 4; ++n) { s[m][n][0] = 0.f; s[m][n][1] = 0.f; s[m][n][2] = 0.f; s[m][n][3] = 0.f; }

    short8 aq[4], bk[4];
#pragma unroll
    for (int m = 0; m < 4; ++m)
        aq[m] = *reinterpret_cast<const short8*>(base + (size_t)(16 * m + rl) * 1536 + qoff + qg * 8);
#pragma unroll
    for (int n = 0; n < 4; ++n)
        bk[n] = *reinterpret_cast<const short8*>(base + (size_t)(16 * n + rl) * 1536 + koff + qg * 8);
#pragma unroll
    for (int m = 0; m < 4; ++m)
#pragma unroll
        for (int n = 0; n < 4; ++n)
            s[m][n] = __builtin_amdgcn_mfma_f32_16x16x32_bf16(aq[m], bk[n], s[m][n], 0, 0, 0);

    const float scale = 0.17677669529663687f;
    const float* bh = biasp + head * 4096;
#pragma unroll
    for (int m = 0; m < 4; ++m) {
#pragma unroll
        for (int r = 0; r < 4; ++r) {
            int row = 16 * m + qg * 4 + r;
            float v0 = s[m][0][r] * scale + bh[row * 64 + rl];
            float v1 = s[m][1][r] * scale + bh[row * 64 + 16 + rl];
            float v2 = s[m][2][r] * scale + bh[row * 64 + 32 + rl];
            float v3 = s[m][3][r] * scale + bh[row * 64 + 48 + rl];
            float mx = fmaxf(fmaxf(v0, v1), fmaxf(v2, v3));
            mx = fmaxf(mx, __shfl_xor(mx, 1));
            mx = fmaxf(mx, __shfl_xor(mx, 2));
            mx = fmaxf(mx, __shfl_xor(mx, 4));
            mx = fmaxf(mx, __shfl_xor(mx, 8));
            v0 = fexp(v0 - mx); v1 = fexp(v1 - mx); v2 = fexp(v2 - mx); v3 = fexp(v3 - mx);
            float sm = v0 + v1 + v2 + v3;
            sm += __shfl_xor(sm, 1);
            sm += __shfl_xor(sm, 2);
            sm += __shfl_xor(sm, 4);
            sm += __shfl_xor(sm, 8);
            float inv = frcp(sm);
            Pl[row][rl]      = f2bf(v0 * inv);
            Pl[row][16 + rl] = f2bf(v1 * inv);
            Pl[row][32 + rl] = f2bf(v2 * inv);
            Pl[row][48 + rl] = f2bf(v3 * inv);
        }
    }
    __syncthreads();

    short8 bv[2][2];
#pragma unroll
    for (int ks = 0; ks < 2; ++ks)
#pragma unroll
        for (int n2 = 0; n2 < 2; ++n2) {
            short8 t;
#pragma unroll
            for (int i = 0; i < 8; ++i)
                t[i] = (short)base[(size_t)(32 * ks + qg * 8 + i) * 1536 + voff + n2 * 16 + rl];
            bv[ks][n2] = t;
        }

    f32x4 acc2[4][2];
#pragma unroll
    for (int m = 0; m < 4; ++m)
#pragma unroll
        for (int n2 = 0; n2 < 2; ++n2) { acc2[m][n2][0] = 0.f; acc2[m][n2][1] = 0.f; acc2[m][n2][2] = 0.f; acc2[m][n2][3] = 0.f; }

#pragma unroll
    for (int m = 0; m < 4; ++m) {
        short8 p0 = *reinterpret_cast<const short8*>(&Pl[16 * m + rl][qg * 8]);
        short8 p1 = *reinterpret_cast<const short8*>(&Pl[16 * m + rl][32 + qg * 8]);
#pragma unroll
        for (int n2 = 0; n2 < 2; ++n2) {
            acc2[m][n2] = __builtin_amdgcn_mfma_f32_16x16x32_bf16(p0, bv[0][n2], acc2[m][n2], 0, 0, 0);
            acc2[m][n2] = __builtin_amdgcn_mfma_f32_16x16x32_bf16(p1, bv[1][n2], acc2[m][n2], 0, 0, 0);
        }
    }
#pragma unroll
    for (int m = 0; m < 4; ++m)
#pragma unroll
        for (int n2 = 0; n2 < 2; ++n2)
#pragma unroll
            for (int r = 0; r < 4; ++r) {
                int row = 16 * m + qg * 4 + r;
                o[(T0 + row) * 512 + head * 32 + n2 * 16 + rl] = f2bf(acc2[m][n2][r]);
            }
}

// ---------------------------------------------------------------------------
// Window-departition: tokens[t_local][c] -> x[B,C,H,W] (coalesced via LDS)
// ---------------------------------------------------------------------------
__global__ __launch_bounds__(256) void k_departition(const unsigned short* __restrict__ tok,
                                                     void* __restrict__ xo,
                                                     int b0, const int* __restrict__ flag) {
    __shared__ unsigned short tile[64][512];
    int isf = flag[0];
    int bh = blockIdx.x, bl = bh >> 6, hh = bh & 63;
    int b = b0 + bl;
    int tid = threadIdx.x;
    int Tb = (bl * 64 + (hh >> 3) * 8) * 64 + (hh & 7) * 8;
    for (int k = 0; k < 16; ++k) {
        int flat = k * 256 + tid;
        int w = flat >> 6, ch = flat & 63;
        int t = Tb + (w >> 3) * 64 + (w & 7);
        short8 v = *reinterpret_cast<const short8*>(tok + (size_t)t * 512 + ch * 8);
        *reinterpret_cast<short8*>(&tile[w][ch * 8]) = v;
    }
    __syncthreads();
    size_t xoff = (((size_t)b * 512) * 64 + hh) * 64;
    if (isf) {
        float* xb = (float*)xo + xoff;
        for (int k = 0; k < 16; ++k) {
            int flat = k * 256 + tid;
            int c = flat >> 3, wc = flat & 7;
            f32x4 a, d;
#pragma unroll
            for (int j = 0; j < 4; ++j) a[j] = bf2f(tile[wc * 8 + j][c]);
#pragma unroll
            for (int j = 0; j < 4; ++j) d[j] = bf2f(tile[wc * 8 + 4 + j][c]);
            *reinterpret_cast<f32x4*>(xb + (size_t)c * 4096 + wc * 8) = a;
            *reinterpret_cast<f32x4*>(xb + (size_t)c * 4096 + wc * 8 + 4) = d;
        }
    } else {
        unsigned short* xb = (unsigned short*)xo + xoff;
        for (int k = 0; k < 16; ++k) {
            int flat = k * 256 + tid;
            int c = flat >> 3, wc = flat & 7;
            short8 v;
#pragma unroll
            for (int j = 0; j < 8; ++j) v[j] = (short)tile[wc * 8 + j][c];
            *reinterpret_cast<short8*>(xb + (size_t)c * 4096 + wc * 8) = v;
        }
    }
}

// ---------------------------------------------------------------------------
extern "C" void kernel_launch(void* const* d_in, const int* in_sizes, int n_in,
                              void* d_out, int out_size, void* d_ws, size_t ws_size,
                              hipStream_t stream) {
    const void* x          = d_in[0];
    const void* g1         = d_in[1];
    const void* be1        = d_in[2];
    const void* g2         = d_in[3];
    const void* be2        = d_in[4];
    const void* qkv_w      = d_in[5];
    const void* qkv_b      = d_in[6];
    const void* merge_w    = d_in[7];
    const void* merge_b    = d_in[8];
    const void* bias_table = d_in[9];
    const void* w1         = d_in[10];
    const void* b1         = d_in[11];
    const void* w2         = d_in[12];
    const void* b2         = d_in[13];
    const int*  rel_idx    = (const int*)d_in[14];

    // Per-token ws need = 9216 B (xw 1024 + h 1024 + qkv 3072 + mid 4096).
    const size_t extra = 8u << 20;
    int CB = 4;
    if      (ws_size >= (size_t)131072 * 9216 + extra) CB = 32;
    else if (ws_size >= (size_t)65536  * 9216 + extra) CB = 16;
    else if (ws_size >= (size_t)32768  * 9216 + extra) CB = 8;
    int nch = 32 / CB;
    size_t tok = (size_t)CB * 4096;

    unsigned short* xw_c     = (unsigned short*)d_ws;
    unsigned short* h_c      = xw_c + tok * 512;
    unsigned short* qkv_c    = h_c + tok * 512;
    unsigned short* mid_c    = qkv_c + tok * 1536;
    unsigned short* qkv_wT   = mid_c + tok * 2048;
    unsigned short* merge_wT = qkv_wT + 1536 * 512;
    unsigned short* w1T      = merge_wT + 512 * 512;
    unsigned short* w2T      = w1T + 2048 * 512;
    unsigned short* vecs     = w2T + 512 * 2048;
    float*          biasp    = (float*)(vecs + 6656);
    int*            flag     = (int*)(biasp + 65536);

    unsigned short* ng1 = vecs + 0,    *nbe1 = vecs + 512;
    unsigned short* ng2 = vecs + 1024, *nbe2 = vecs + 1536;
    unsigned short* nqb = vecs + 2048, *nmb  = vecs + 3584;
    unsigned short* nb1 = vecs + 4096, *nb2  = vecs + 6144;

    // --- prep (4 dispatches)
    k_detect<<<1, 64, 0, stream>>>(g1, flag);
    k_cvt_all<<<26, 256, 0, stream>>>(g1, be1, g2, be2, qkv_b, merge_b, b1, b2, vecs, flag);
    k_transpose_all<<<3072, 256, 0, stream>>>(qkv_w, merge_w, w1, w2,
                                              qkv_wT, merge_wT, w1T, w2T, flag);
    k_prep_bias<<<256, 256, 0, stream>>>(bias_table, rel_idx, biasp, flag);

    int mtiles = (int)(tok / 256);
    int M = (int)tok;
    for (int c = 0; c < nch; ++c) {
        int b0 = c * CB;
        k_partition_ln<<<CB * 64, 256, 0, stream>>>(x, ng1, nbe1, xw_c, h_c, b0, flag);
        k_gemm18<0><<<dim3(mtiles, 6), 512, 0, stream>>>(h_c, qkv_wT, nqb, nullptr, qkv_c, M, 1536, 512);
        k_attn<<<CB * 1024, 64, 0, stream>>>(qkv_c, biasp, h_c);            // o -> h_c (h dead)
        k_gemm18<1><<<dim3(mtiles, 2), 512, 0, stream>>>(h_c, merge_wT, nmb, xw_c, xw_c, M, 512, 512);
        k_ln<<<(int)(tok / 4), 256, 0, stream>>>(xw_c, ng2, nbe2, h_c);
        k_gemm18<2><<<dim3(mtiles, 8), 512, 0, stream>>>(h_c, w1T, nb1, nullptr, mid_c, M, 2048, 512);
        k_gemm18<1><<<dim3(mtiles, 2), 512, 0, stream>>>(mid_c, w2T, nb2, xw_c, qkv_c, M, 512, 2048);
        k_departition<<<CB * 64, 256, 0, stream>>>(qkv_c, d_out, b0, flag);
    }
}